// Round 10
// baseline (132.953 us; speedup 1.0000x reference)
//
#include <hip/hip_runtime.h>
#include <cmath>

#define BB 2
#define SS 2048
#define EE 512
#define HH 8
#define DD 64

typedef unsigned short u16t;
typedef __bf16 bf16x8 __attribute__((ext_vector_type(8)));
typedef float f32x4 __attribute__((ext_vector_type(4)));

__device__ __forceinline__ float bf2f(u16t u){
    union{unsigned int i; float f;} c; c.i = ((unsigned int)u)<<16; return c.f;
}
__device__ __forceinline__ u16t f2bf(float x){
    union{float f; unsigned int i;} c; c.f = x;
    return (u16t)((c.i + 0x7fffu + ((c.i>>16)&1u))>>16);
}
__device__ __forceinline__ unsigned cvtpk(float a, float b){
    unsigned r;
    asm("v_cvt_pk_bf16_f32 %0, %1, %2" : "=v"(r) : "v"(a), "v"(b));
    return r;   // a -> low 16, b -> high 16 (RNE)
}
__device__ __forceinline__ float fast_tanh(float x){
    float e = __expf(2.f*x); return 1.f - 2.f/(e+1.f);
}
__device__ __forceinline__ float fast_atanh(float x){
    return 0.5f*__logf((1.f+x)/(1.f-x));
}
__device__ __forceinline__ f32x4 mfma16(bf16x8 a, bf16x8 b, f32x4 c){
    return __builtin_amdgcn_mfma_f32_16x16x32_bf16(a,b,c,0,0,0);
}
// chunk bookkeeping: QBLK=64, chunk=8 kv-tiles. qi in [0,32):
// nch(qi) = (qi>>3)+1 ; offq8(qi) = sum_{q<qi} nch(q) ; total per bh = 80
__device__ __forceinline__ int offq8(int qi){
    int a = qi >> 3;
    return 4*a*(a+1) + (qi & 7)*(a+1);
}

// ---------------- Kernel B: U = logmap0(X) @ W^T + b, fused (fp32 in) ---------
// logmap0(x) = s*x with per-row scalar s = atanh(|x|)/|x| -> commutes with GEMM:
// U = s*(x@W^T) + b. Reads raw fp32 X/W, converts bf16 inline (cvtpk), scales
// in the epilogue. Same 64x64-tile / 1536-block / double-barrier skeleton as
// the proven k_proj; swapped mfma(W,X) so each lane's 16 outputs share one row.
__global__ __launch_bounds__(256) void k_proj(const float* __restrict__ qp,
        const float* __restrict__ kp, const float* __restrict__ vp,
        const float* __restrict__ Wq, const float* __restrict__ Wk,
        const float* __restrict__ Wv,
        const float* __restrict__ bq, const float* __restrict__ bk,
        const float* __restrict__ bv,
        u16t* __restrict__ U){
    __shared__ __align__(16) u16t Wl[64][72];
    int bx = blockIdx.x;                 // 3 * 64 * 8
    int t = bx >> 9; int rem = bx & 511;
    int m0 = (rem >> 3) << 6; int n0 = (rem & 7) << 6;
    int tid = threadIdx.x; int wvi = tid>>6; int lane = tid&63;
    int l15 = lane & 15; int l4 = lane >> 4;
    const float* X  = (t==0 ? qp : (t==1 ? kp : vp));
    const float* Wf = (t==0 ? Wq : (t==1 ? Wk : Wv));
    const float* bias = (t==0 ? bq : (t==1 ? bk : bv));
    int arow = m0 + 16*wvi + l15;
    const float* xr = X + (size_t)arow*EE;
    // per-row logmap0 scale: s = atanh(min(|x|,MAXN))/|x| (4 lanes per row)
    float pn = 0.f;
    #pragma unroll
    for (int i=0;i<32;++i){
        float4 v = *(const float4*)(xr + l4*128 + i*4);
        pn += v.x*v.x + v.y*v.y + v.z*v.z + v.w*v.w;
    }
    pn += __shfl_xor(pn,16,64); pn += __shfl_xor(pn,32,64);
    float nn = sqrtf(fmaxf(pn, 1e-12f));
    float sc = fast_atanh(fminf(nn, 1.0f-1e-5f)) / nn;
    // GEMM, K=512 in 8 steps of 64; W staged bf16 in LDS, A converted inline
    f32x4 z = {0.f,0.f,0.f,0.f};
    f32x4 acc[4] = {z,z,z,z};
    int rr = tid >> 2; int cc = (tid & 3) * 16;   // staging: W row rr, cols cc..cc+15
    const float* wrow = Wf + (size_t)(n0+rr)*EE;
    float4 w0 = *(const float4*)(wrow + cc);
    float4 w1 = *(const float4*)(wrow + cc + 4);
    float4 w2 = *(const float4*)(wrow + cc + 8);
    float4 w3 = *(const float4*)(wrow + cc + 12);
    float4 a00 = *(const float4*)(xr + l4*8);
    float4 a01 = *(const float4*)(xr + l4*8 + 4);
    float4 a10 = *(const float4*)(xr + 32 + l4*8);
    float4 a11 = *(const float4*)(xr + 32 + l4*8 + 4);
    for (int ks=0; ks<8; ++ks){
        int k0 = ks*64;
        uint4 wa, wb;
        wa.x = cvtpk(w0.x,w0.y); wa.y = cvtpk(w0.z,w0.w);
        wa.z = cvtpk(w1.x,w1.y); wa.w = cvtpk(w1.z,w1.w);
        wb.x = cvtpk(w2.x,w2.y); wb.y = cvtpk(w2.z,w2.w);
        wb.z = cvtpk(w3.x,w3.y); wb.w = cvtpk(w3.z,w3.w);
        *(uint4*)&Wl[rr][cc]   = wa;
        *(uint4*)&Wl[rr][cc+8] = wb;
        union { uint4 u; bf16x8 v; } ua0, ua1;
        ua0.u.x = cvtpk(a00.x,a00.y); ua0.u.y = cvtpk(a00.z,a00.w);
        ua0.u.z = cvtpk(a01.x,a01.y); ua0.u.w = cvtpk(a01.z,a01.w);
        ua1.u.x = cvtpk(a10.x,a10.y); ua1.u.y = cvtpk(a10.z,a10.w);
        ua1.u.z = cvtpk(a11.x,a11.y); ua1.u.w = cvtpk(a11.z,a11.w);
        __syncthreads();
        if (ks < 7){
            int kn = k0 + 64;
            w0 = *(const float4*)(wrow + kn + cc);
            w1 = *(const float4*)(wrow + kn + cc + 4);
            w2 = *(const float4*)(wrow + kn + cc + 8);
            w3 = *(const float4*)(wrow + kn + cc + 12);
            a00 = *(const float4*)(xr + kn + l4*8);
            a01 = *(const float4*)(xr + kn + l4*8 + 4);
            a10 = *(const float4*)(xr + kn + 32 + l4*8);
            a11 = *(const float4*)(xr + kn + 32 + l4*8 + 4);
        }
        #pragma unroll
        for (int f=0; f<4; ++f){
            bf16x8 b0 = *(const bf16x8*)&Wl[f*16+l15][l4*8];
            bf16x8 b1 = *(const bf16x8*)&Wl[f*16+l15][32+l4*8];
            acc[f] = mfma16(b0, ua0.v, acc[f]);   // swapped: rows=n, cols=m
            acc[f] = mfma16(b1, ua1.v, acc[f]);
        }
        __syncthreads();
    }
    // epilogue: col = lane's own arow -> s is a per-lane scalar
    u16t* Ut = U + (size_t)t*4096*EE;
    #pragma unroll
    for (int f=0; f<4; ++f){
        float4 b4 = *(const float4*)&bias[n0 + f*16 + l4*4];
        uint2 u2;
        u2.x = cvtpk(fmaf(sc,acc[f][0],b4.x), fmaf(sc,acc[f][1],b4.y));
        u2.y = cvtpk(fmaf(sc,acc[f][2],b4.z), fmaf(sc,acc[f][3],b4.w));
        *(uint2*)(Ut + (size_t)arow*EE + n0 + f*16 + l4*4) = u2;
    }
}

// ---------------- Kernel C: expmap0 + head split + norms (V stored transposed) --
__global__ __launch_bounds__(256) void k_expmap_split(const u16t* __restrict__ U,
        u16t* __restrict__ Q, u16t* __restrict__ K, u16t* __restrict__ VT,
        float* __restrict__ qn2, float* __restrict__ kn2, float* __restrict__ lam1){
    int gr = blockIdx.x*4 + (threadIdx.x>>6);   // 0..12287
    int t = gr >> 12;
    int row = gr & 4095;
    int b = row >> 11; int s = row & 2047;
    int lane = threadIdx.x & 63;
    const u16t* u = U + ((size_t)t*4096 + row)*EE;
    uint4 raw = *(const uint4*)(u + lane*8);
    const u16t* rs = (const u16t*)&raw;
    float x[8];
    #pragma unroll
    for (int i=0;i<8;++i) x[i] = bf2f(rs[i]);
    float p = 0.f;
    #pragma unroll
    for (int i=0;i<8;++i) p += x[i]*x[i];
    #pragma unroll
    for (int off=32; off>=1; off>>=1) p += __shfl_xor(p, off, 64);
    float n = sqrtf(fmaxf(p, 1e-12f));
    float f = fast_tanh(n)/n;
    float y[8]; u16t yb[8];
    float hp = 0.f;
    #pragma unroll
    for (int i=0;i<8;++i){
        yb[i] = f2bf(f*x[i]);
        y[i]  = bf2f(yb[i]);        // rounded values -> consistent norms
        hp += y[i]*y[i];
    }
    #pragma unroll
    for (int off=1; off<8; off<<=1) hp += __shfl_xor(hp, off, 64);
    hp = fminf(hp, 0.99999988f);    // guard: keep strictly below 1 for rcp path
    int h = lane >> 3;
    size_t ih = (size_t)(b*HH + h)*SS + s;
    if (t == 0){
        uint4 o;
        o.x=(unsigned)yb[0]|((unsigned)yb[1]<<16); o.y=(unsigned)yb[2]|((unsigned)yb[3]<<16);
        o.z=(unsigned)yb[4]|((unsigned)yb[5]<<16); o.w=(unsigned)yb[6]|((unsigned)yb[7]<<16);
        *(uint4*)(Q + ih*DD + (lane&7)*8) = o;
        if ((lane&7)==0) qn2[ih] = hp;
    } else if (t == 1){
        uint4 o;
        o.x=(unsigned)yb[0]|((unsigned)yb[1]<<16); o.y=(unsigned)yb[2]|((unsigned)yb[3]<<16);
        o.z=(unsigned)yb[4]|((unsigned)yb[5]<<16); o.w=(unsigned)yb[6]|((unsigned)yb[7]<<16);
        *(uint4*)(K + ih*DD + (lane&7)*8) = o;
        if ((lane&7)==0) kn2[ih] = hp;
    } else {
        float lam = 2.f / fmaxf(1.f - hp, 1e-6f);
        size_t bh = (size_t)(b*HH + h);
        int d0 = (lane&7)*8;
        #pragma unroll
        for (int i=0;i<8;++i)
            VT[(bh*DD + d0 + i)*SS + s] = f2bf(y[i]*lam);   // V^T, scaled by lambda
        if ((lane&7)==0) lam1[ih] = lam - 1.f;
    }
}

// ---------------- Kernel D: fused causal hyperbolic attention ------------------
// QBLK=64 (4 waves x 16q), KVBLK=64, chunk=8. Swapped-operand MFMAs; w packed
// via v_cvt_pk_bf16_f32; fast path w=rcp(zz) when tau'==1 && gamma==0 (exact:
// exp(-1*dist+0) == 1/zz), general log/exp path otherwise.
#define EW_BLOCK(DO_DIAG, FASTW)                                              \
    _Pragma("unroll")                                                         \
    for (int f=0; f<4; ++f){                                                  \
        float4 kn24 = *(const float4*)&kn2s[f*16 + l4*4];                     \
        float4 akf4 = *(const float4*)&akfs[f*16 + l4*4];                     \
        float4 l14  = *(const float4*)&l1s [f*16 + l4*4];                     \
        float wv4[4];                                                         \
        _Pragma("unroll")                                                     \
        for (int r=0; r<4; ++r){                                              \
            float sq  = fmaxf(fmaf(-2.f, c[f][r], qv + ((const float*)&kn24)[r]), 0.f); \
            float co  = fminf(aq2 * ((const float*)&akf4)[r], 2e6f);          \
            float rho = sq * co;                                              \
            float tt  = fmaf(rho, rho, rho + rho);                            \
            float zz  = 1.f + rho + __builtin_amdgcn_sqrtf(tt);               \
            float w;                                                          \
            if (FASTW){ w = __builtin_amdgcn_rcpf(zz); }                      \
            else { float L = __builtin_amdgcn_logf(zz);                       \
                   w = __builtin_amdgcn_exp2f(fmaf(-tauexp, L, gm2)); }       \
            if (DO_DIAG && (kv0 + f*16 + l4*4 + r) > qrow) w = 0.f;           \
            dn = fmaf(w, ((const float*)&l14)[r], dn);                        \
            wv4[r] = w;                                                       \
        }                                                                     \
        uint2 u2; u2.x = cvtpk(wv4[0], wv4[1]); u2.y = cvtpk(wv4[2], wv4[3]); \
        *(uint2*)&Wt[16*wv + l15][f*16 + l4*4] = u2;                          \
    }

__global__ __launch_bounds__(256,5) void k_attn(const u16t* __restrict__ Q,
        const u16t* __restrict__ K, const u16t* __restrict__ VT,
        const float* __restrict__ qn2, const float* __restrict__ kn2,
        const float* __restrict__ lam1, const float* __restrict__ taup,
        const float* __restrict__ gammap,
        float* __restrict__ pnum, float* __restrict__ pden){
    __shared__ __align__(16) u16t Kt[64][72];
    __shared__ __align__(16) u16t Vt[64][72];   // V^T tile: [d][kv]
    __shared__ __align__(16) u16t Wt[64][72];   // w[q][kv], per-wave row stripes
    __shared__ float kn2s[64], akfs[64], l1s[64];
    int bx = blockIdx.x;
    int bh = bx & 15;               // low bits -> per-bh XCD/L2 affinity
    int u = bx >> 4;                // 0..79
    int v = 79 - u;                 // heavy qi first
    int qi = 31;
    while (offq8(qi) > v) --qi;
    int c0 = v - offq8(qi);
    int jt0 = c0 << 3;
    int jt1 = min(jt0 + 8, qi + 1);
    int s0 = qi << 6;
    int tid = threadIdx.x; int wv = tid>>6; int lane = tid&63;
    int l15 = lane & 15; int l4 = lane >> 4;
    float tauexp = __expf(taup[0]);
    float gm2 = gammap[0] * 1.44269504088896340736f;  // gamma * log2(e)
    bool fastw = (tauexp == 1.0f) && (gm2 == 0.0f);
    size_t base = (size_t)bh * SS;
    int qrow = s0 + 16*wv + l15;    // this lane's global q row
    bf16x8 aQ0 = *(const bf16x8*)(Q + (base + qrow)*DD + l4*8);
    bf16x8 aQ1 = *(const bf16x8*)(Q + (base + qrow)*DD + 32 + l4*8);
    float qv  = qn2[base + qrow];
    float aq2 = 2.f * __builtin_amdgcn_rcpf(fmaxf(1.f - qv, 1e-6f));
    f32x4 z4 = {0.f,0.f,0.f,0.f};
    f32x4 num[4] = {z4,z4,z4,z4};
    float dn = 0.f;
    int rr = tid >> 2; int cc = (tid & 3) << 4;
    // register prefetch (T14)
    uint4 pka0, pka1, pva0, pva1; float pkn = 0.f, pl1 = 0.f;
    {   // prologue: load tile jt0
        int kv0 = jt0 << 6;
        const uint4* gk = (const uint4*)(K + (base + kv0 + rr)*DD + cc);
        pka0 = gk[0]; pka1 = gk[1];
        const uint4* gv = (const uint4*)(VT + ((size_t)bh*DD + rr)*SS + kv0 + cc);
        pva0 = gv[0]; pva1 = gv[1];
        if (tid < 64){ pkn = kn2[base+kv0+tid]; pl1 = lam1[base+kv0+tid]; }
    }
    for (int jt=jt0; jt<jt1; ++jt){
        // commit prefetched tile to LDS
        *(uint4*)&Kt[rr][cc]   = pka0;
        *(uint4*)&Kt[rr][cc+8] = pka1;
        *(uint4*)&Vt[rr][cc]   = pva0;
        *(uint4*)&Vt[rr][cc+8] = pva1;
        if (tid < 64){
            kn2s[tid] = pkn;
            l1s[tid]  = pl1;
            akfs[tid] = __builtin_amdgcn_rcpf(fmaxf(1.f - pkn, 1e-6f));
        }
        __syncthreads();
        // issue next tile's global loads (overlap with compute below)
        if (jt+1 < jt1){
            int kv0n = (jt+1) << 6;
            const uint4* gk = (const uint4*)(K + (base + kv0n + rr)*DD + cc);
            pka0 = gk[0]; pka1 = gk[1];
            const uint4* gv = (const uint4*)(VT + ((size_t)bh*DD + rr)*SS + kv0n + cc);
            pva0 = gv[0]; pva1 = gv[1];
            if (tid < 64){ pkn = kn2[base+kv0n+tid]; pl1 = lam1[base+kv0n+tid]; }
        }
        int kv0 = jt << 6;
        // QK^T swapped: c[f][r] = dot(q=l15, k=16f+4l4+r)
        f32x4 c[4] = {z4,z4,z4,z4};
        #pragma unroll
        for (int f=0; f<4; ++f){
            bf16x8 kb0 = *(const bf16x8*)&Kt[f*16+l15][l4*8];
            bf16x8 kb1 = *(const bf16x8*)&Kt[f*16+l15][32+l4*8];
            c[f] = mfma16(kb0, aQ0, c[f]);
            c[f] = mfma16(kb1, aQ1, c[f]);
        }
        // elementwise distance -> w, packed to Wt
        if (jt == qi){
            if (fastw) { EW_BLOCK(true, true) } else { EW_BLOCK(true, false) }
        } else {
            if (fastw) { EW_BLOCK(false, true) } else { EW_BLOCK(false, false) }
        }
        // PV swapped: num[f][r] = M[q=l15][d=16f+4l4+r]
        bf16x8 pw0 = *(const bf16x8*)&Wt[16*wv + l15][l4*8];
        bf16x8 pw1 = *(const bf16x8*)&Wt[16*wv + l15][32 + l4*8];
        #pragma unroll
        for (int f=0; f<4; ++f){
            bf16x8 vb0 = *(const bf16x8*)&Vt[f*16+l15][l4*8];
            bf16x8 vb1 = *(const bf16x8*)&Vt[f*16+l15][32+l4*8];
            num[f] = mfma16(vb0, pw0, num[f]);
            num[f] = mfma16(vb1, pw1, num[f]);
        }
        __syncthreads();
    }
    // den: reduce over the 16 k's held per lane -> over l4 groups
    dn += __shfl_xor(dn, 16, 64);
    dn += __shfl_xor(dn, 32, 64);
    // store partials: pn[q][d] with d-consecutive float4
    size_t pidx = (size_t)bh*80 + offq8(qi) + c0;
    float* pn = pnum + pidx*4096;
    #pragma unroll
    for (int f=0; f<4; ++f)
        *(f32x4*)&pn[(16*wv + l15)*64 + f*16 + l4*4] = num[f];
    if (l4 == 0) pden[pidx*64 + 16*wv + l15] = dn;
}

// ---------------- Kernel E: combine partials + gyromidpoint + logmap + expmap --
// block = (b, 16-row s-tile); thread = (row, head, half): tid = row*16 + h*2 + half
__global__ __launch_bounds__(256) void k_post(const float* __restrict__ pnum,
        const float* __restrict__ pden, float* __restrict__ out, float beta){
    int bx = blockIdx.x;              // 2 b x 128 s-tiles
    int b = bx >> 7; int stile = bx & 127;
    int tid = threadIdx.x;
    int row = tid >> 4; int h = (tid >> 1) & 7; int half = tid & 1;
    int s = stile*16 + row;
    int qi = s >> 6; int rowin = s & 63;
    int nch = (qi >> 3) + 1;
    size_t pb = (size_t)(b*HH + h)*80 + offq8(qi);
    float mv[32];
    #pragma unroll
    for (int i=0;i<32;++i) mv[i] = 0.f;
    float den = 0.f;
    for (int cc=0; cc<nch; ++cc){
        const float* pn = pnum + (pb+cc)*4096 + rowin*64 + half*32;
        #pragma unroll
        for (int i=0;i<8;++i){
            float4 v = *(const float4*)(pn + i*4);
            mv[i*4+0]+=v.x; mv[i*4+1]+=v.y; mv[i*4+2]+=v.z; mv[i*4+3]+=v.w;
        }
        den += pden[(pb+cc)*64 + rowin];
    }
    float invd = 1.f / fmaxf(den, 1e-6f);
    float mn2h = 0.f;
    #pragma unroll
    for (int i=0;i<32;++i){ mv[i] *= invd; mn2h += mv[i]*mv[i]; }
    // per-head norm over 64 dims: pair (half) reduce
    float mn2 = mn2h + __shfl_xor(mn2h, 1, 64);
    float mn = sqrtf(fmaxf(mn2, 1e-12f));
    float g = beta * 0.5f * fast_atanh(fminf(mn, 1.0f-1e-5f)) / mn;   // t_h = g*m_h
    // E-norm^2 = sum_h g^2*mn2 : reduce over h bits (1,2,3 of tid>>1)
    float tn = g*g*mn2;
    tn += __shfl_xor(tn, 2, 64);
    tn += __shfl_xor(tn, 4, 64);
    tn += __shfl_xor(tn, 8, 64);
    float en = sqrtf(fmaxf(tn, 1e-12f));
    float f = fast_tanh(en)/en;
    float gf = g * f;
    float* dst = out + ((size_t)(b*SS + s))*EE + h*DD + half*32;
    #pragma unroll
    for (int i=0;i<8;++i){
        float4 v = {gf*mv[i*4+0], gf*mv[i*4+1], gf*mv[i*4+2], gf*mv[i*4+3]};
        *(float4*)(dst + i*4) = v;
    }
}

extern "C" void kernel_launch(void* const* d_in, const int* in_sizes, int n_in,
                              void* d_out, int out_size, void* d_ws, size_t ws_size,
                              hipStream_t stream) {
    const float* q_in  = (const float*)d_in[0];
    const float* k_in  = (const float*)d_in[1];
    const float* v_in  = (const float*)d_in[2];
    const float* Wq    = (const float*)d_in[3];
    const float* Wk    = (const float*)d_in[4];
    const float* Wv    = (const float*)d_in[5];
    const float* bq    = (const float*)d_in[6];
    const float* bk    = (const float*)d_in[7];
    const float* bv    = (const float*)d_in[8];
    const float* tau   = (const float*)d_in[9];
    const float* gamma = (const float*)d_in[10];
    float* out = (float*)d_out;

    char* ws = (char*)d_ws;
    u16t*  Ub   = (u16t*)(ws + 0);            // 12,582,912 B bf16
    u16t*  Qb   = (u16t*)(ws + 12582912);     //  4,194,304 B
    u16t*  Kb   = (u16t*)(ws + 16777216);     //  4,194,304 B
    u16t*  VTb  = (u16t*)(ws + 20971520);     //  4,194,304 B  (V^T * lambda)
    float* qn2  = (float*)(ws + 25165824);    //    131,072 B
    float* kn2  = (float*)(ws + 25296896);    //    131,072 B
    float* lam1 = (float*)(ws + 25427968);    //    131,072 B
    float* pnum = (float*)(ws + 25559040);    // 16*80*4096*4 = 20,971,520 B
    float* pden = (float*)(ws + 46530560);    // 16*80*64*4   =    327,680 B

    // beta-concatenation ratio: exp(lbeta(E/2,1/2) - lbeta(D/2,1/2))
    double lb1 = std::lgamma(256.0) + std::lgamma(0.5) - std::lgamma(256.5);
    double lb2 = std::lgamma(32.0)  + std::lgamma(0.5) - std::lgamma(32.5);
    float beta = (float)std::exp(lb1 - lb2);

    k_proj<<<1536, 256, 0, stream>>>(q_in, k_in, v_in, Wq, Wk, Wv,
                                     bq, bk, bv, Ub);
    k_expmap_split<<<3072, 256, 0, stream>>>(Ub, Qb, Kb, VTb, qn2, kn2, lam1);
    k_attn<<<1280, 256, 0, stream>>>(Qb, Kb, VTb, qn2, kn2, lam1, tau, gamma,
                                     pnum, pden);
    k_post<<<256, 256, 0, stream>>>(pnum, pden, out, beta);
}

// Round 11
// 92.660 us; speedup vs baseline: 1.4348x; 1.4348x over previous
//
#include <hip/hip_runtime.h>
#include <cmath>

#define BB 2
#define SS 2048
#define EE 512
#define HH 8
#define DD 64

typedef unsigned short u16t;
typedef __bf16 bf16x8 __attribute__((ext_vector_type(8)));
typedef float f32x4 __attribute__((ext_vector_type(4)));

__device__ __forceinline__ float bf2f(u16t u){
    union{unsigned int i; float f;} c; c.i = ((unsigned int)u)<<16; return c.f;
}
__device__ __forceinline__ u16t f2bf(float x){
    union{float f; unsigned int i;} c; c.f = x;
    return (u16t)((c.i + 0x7fffu + ((c.i>>16)&1u))>>16);
}
__device__ __forceinline__ unsigned cvtpk(float a, float b){
    unsigned r;
    asm("v_cvt_pk_bf16_f32 %0, %1, %2" : "=v"(r) : "v"(a), "v"(b));
    return r;   // a -> low 16, b -> high 16 (RNE)
}
__device__ __forceinline__ float fast_tanh(float x){
    float e = __expf(2.f*x); return 1.f - 2.f/(e+1.f);
}
__device__ __forceinline__ float fast_atanh(float x){
    return 0.5f*__logf((1.f+x)/(1.f-x));
}
__device__ __forceinline__ f32x4 mfma16(bf16x8 a, bf16x8 b, f32x4 c){
    return __builtin_amdgcn_mfma_f32_16x16x32_bf16(a,b,c,0,0,0);
}
// chunk bookkeeping: QBLK=64, chunk=16 kv-tiles. qi in [0,32):
// nch(qi) = (qi>>4)+1 ; offq16(qi) = qi (qi<16) else 2*qi-16 ; total per bh = 48
__device__ __forceinline__ int offq16(int qi){
    return (qi < 16) ? qi : (2*qi - 16);
}

// ---------------- Kernel A: logmap0 rows (bf16 out) + W cvt, merged ------------
__global__ __launch_bounds__(256) void k_pre(const float* __restrict__ qp,
                                             const float* __restrict__ kp,
                                             const float* __restrict__ vp,
                                             u16t* __restrict__ Tlog,
                                             const float* __restrict__ Wq,
                                             const float* __restrict__ Wk,
                                             const float* __restrict__ Wv,
                                             u16t* __restrict__ Wb){
    int bx = blockIdx.x;
    if (bx < 3072){
        int gr = bx*4 + (threadIdx.x>>6);   // 0..12287
        int t = gr >> 12;
        int row = gr & 4095;
        int lane = threadIdx.x & 63;
        const float* src = (t==0 ? qp : (t==1 ? kp : vp)) + (size_t)row*EE;
        const float4* s4 = (const float4*)(src + lane*8);
        float4 a = s4[0], b = s4[1];
        float x[8] = {a.x,a.y,a.z,a.w,b.x,b.y,b.z,b.w};
        float p = 0.f;
        #pragma unroll
        for (int i=0;i<8;++i) p += x[i]*x[i];
        #pragma unroll
        for (int off=32; off>=1; off>>=1) p += __shfl_xor(p, off, 64);
        float n = sqrtf(fmaxf(p, 1e-12f));
        float f = fast_atanh(fminf(n, 1.0f-1e-5f)) / n;
        u16t yb[8];
        #pragma unroll
        for (int i=0;i<8;++i) yb[i] = f2bf(f*x[i]);
        uint4 o;
        o.x = (unsigned)yb[0] | ((unsigned)yb[1]<<16);
        o.y = (unsigned)yb[2] | ((unsigned)yb[3]<<16);
        o.z = (unsigned)yb[4] | ((unsigned)yb[5]<<16);
        o.w = (unsigned)yb[6] | ((unsigned)yb[7]<<16);
        *(uint4*)(Tlog + ((size_t)(t*4096+row)*EE + lane*8)) = o;
    } else {
        int idx = ((bx-3072)*256 + threadIdx.x)*4;     // 3*512*512 total
        int t = idx >> 18;
        int off = idx & 262143;
        const float* W = (t==0 ? Wq : (t==1 ? Wk : Wv));
        float4 a = *(const float4*)(W + off);
        uint2 o;
        o.x = (unsigned)f2bf(a.x) | ((unsigned)f2bf(a.y)<<16);
        o.y = (unsigned)f2bf(a.z) | ((unsigned)f2bf(a.w)<<16);
        *(uint2*)(Wb + idx) = o;
    }
}

// ---------------- Kernel B: U = Tlog @ W^T + b (MFMA GEMM, bf16 out) -----------
// Swapped operands: D = mfma(W, T) -> lane holds 4 consecutive n-cols per f
// (cvtpk + uint2 stores, float4 bias) instead of 16 scalar stores.
__global__ __launch_bounds__(256) void k_proj(const u16t* __restrict__ Tlog,
                                              const u16t* __restrict__ Wb,
                                              const float* __restrict__ bq,
                                              const float* __restrict__ bk,
                                              const float* __restrict__ bv,
                                              u16t* __restrict__ U){
    __shared__ __align__(16) u16t Wl[64][72];
    int bx = blockIdx.x;                 // 3 * 64 * 8
    int t = bx >> 9; int rem = bx & 511;
    int m0 = (rem >> 3) << 6; int n0 = (rem & 7) << 6;
    int tid = threadIdx.x; int wv = tid>>6; int lane = tid&63;
    int l15 = lane & 15; int l4 = lane >> 4;
    const u16t* Tt = Tlog + (size_t)t*4096*EE;
    const u16t* Wt = Wb + (size_t)t*EE*EE;
    const float* bias = (t==0 ? bq : (t==1 ? bk : bv));
    f32x4 z = {0.f,0.f,0.f,0.f};
    f32x4 acc[4] = {z,z,z,z};
    int arow = m0 + 16*wv + l15;
    int rr = tid >> 2; int cc = (tid & 3) * 16;
    uint4 w0, w1;
    {   // prologue: W-tile ks=0
        const uint4* g = (const uint4*)(Wt + (size_t)(n0+rr)*EE + cc);
        w0 = g[0]; w1 = g[1];
    }
    for (int ks=0; ks<8; ++ks){
        int k0 = ks*64;
        *(uint4*)&Wl[rr][cc]   = w0;
        *(uint4*)&Wl[rr][cc+8] = w1;
        __syncthreads();
        if (ks < 7){
            const uint4* g = (const uint4*)(Wt + (size_t)(n0+rr)*EE + k0 + 64 + cc);
            w0 = g[0]; w1 = g[1];
        }
        bf16x8 a0 = *(const bf16x8*)(Tt + (size_t)arow*EE + k0 + l4*8);
        bf16x8 a1 = *(const bf16x8*)(Tt + (size_t)arow*EE + k0 + 32 + l4*8);
        #pragma unroll
        for (int f=0; f<4; ++f){
            bf16x8 b0 = *(const bf16x8*)&Wl[f*16+l15][l4*8];
            bf16x8 b1 = *(const bf16x8*)&Wl[f*16+l15][32+l4*8];
            acc[f] = mfma16(b0, a0, acc[f]);   // swapped: rows=n, cols=m
            acc[f] = mfma16(b1, a1, acc[f]);
        }
        __syncthreads();
    }
    u16t* Ut = U + (size_t)t*4096*EE;
    int mrow = m0 + 16*wv + l15;
    #pragma unroll
    for (int f=0; f<4; ++f){
        float4 b4 = *(const float4*)&bias[n0 + f*16 + l4*4];
        uint2 u2;
        u2.x = cvtpk(acc[f][0]+b4.x, acc[f][1]+b4.y);
        u2.y = cvtpk(acc[f][2]+b4.z, acc[f][3]+b4.w);
        *(uint2*)(Ut + (size_t)mrow*EE + n0 + f*16 + l4*4) = u2;
    }
}

// ---------------- Kernel C: expmap0 + head split + norms (V stored transposed) --
__global__ __launch_bounds__(256) void k_expmap_split(const u16t* __restrict__ U,
        u16t* __restrict__ Q, u16t* __restrict__ K, u16t* __restrict__ VT,
        float* __restrict__ qn2, float* __restrict__ kn2, float* __restrict__ lam1){
    int gr = blockIdx.x*4 + (threadIdx.x>>6);   // 0..12287
    int t = gr >> 12;
    int row = gr & 4095;
    int b = row >> 11; int s = row & 2047;
    int lane = threadIdx.x & 63;
    const u16t* u = U + ((size_t)t*4096 + row)*EE;
    uint4 raw = *(const uint4*)(u + lane*8);
    const u16t* rs = (const u16t*)&raw;
    float x[8];
    #pragma unroll
    for (int i=0;i<8;++i) x[i] = bf2f(rs[i]);
    float p = 0.f;
    #pragma unroll
    for (int i=0;i<8;++i) p += x[i]*x[i];
    #pragma unroll
    for (int off=32; off>=1; off>>=1) p += __shfl_xor(p, off, 64);
    float n = sqrtf(fmaxf(p, 1e-12f));
    float f = fast_tanh(n)/n;
    float y[8]; u16t yb[8];
    float hp = 0.f;
    #pragma unroll
    for (int i=0;i<8;++i){
        yb[i] = f2bf(f*x[i]);
        y[i]  = bf2f(yb[i]);        // rounded values -> consistent norms
        hp += y[i]*y[i];
    }
    #pragma unroll
    for (int off=1; off<8; off<<=1) hp += __shfl_xor(hp, off, 64);
    hp = fminf(hp, 0.99999988f);    // guard: keep strictly below 1 for rcp path
    int h = lane >> 3;
    size_t ih = (size_t)(b*HH + h)*SS + s;
    if (t == 0){
        uint4 o;
        o.x=(unsigned)yb[0]|((unsigned)yb[1]<<16); o.y=(unsigned)yb[2]|((unsigned)yb[3]<<16);
        o.z=(unsigned)yb[4]|((unsigned)yb[5]<<16); o.w=(unsigned)yb[6]|((unsigned)yb[7]<<16);
        *(uint4*)(Q + ih*DD + (lane&7)*8) = o;
        if ((lane&7)==0) qn2[ih] = hp;
    } else if (t == 1){
        uint4 o;
        o.x=(unsigned)yb[0]|((unsigned)yb[1]<<16); o.y=(unsigned)yb[2]|((unsigned)yb[3]<<16);
        o.z=(unsigned)yb[4]|((unsigned)yb[5]<<16); o.w=(unsigned)yb[6]|((unsigned)yb[7]<<16);
        *(uint4*)(K + ih*DD + (lane&7)*8) = o;
        if ((lane&7)==0) kn2[ih] = hp;
    } else {
        float lam = 2.f / fmaxf(1.f - hp, 1e-6f);
        size_t bh = (size_t)(b*HH + h);
        int d0 = (lane&7)*8;
        #pragma unroll
        for (int i=0;i<8;++i)
            VT[(bh*DD + d0 + i)*SS + s] = f2bf(y[i]*lam);   // V^T, scaled by lambda
        if ((lane&7)==0) lam1[ih] = lam - 1.f;
    }
}

// ---------------- Kernel D: fused causal hyperbolic attention ------------------
// QBLK=64 (4 waves x 16q), KVBLK=64, chunk=16. Double-buffered K/V LDS ->
// SINGLE barrier per kv-tile (commit targets buf^1 while others read buf; Wt is
// wave-private). Swapped-operand MFMAs; cvt_pk packing; fastw rcp path.
#define EW_BLOCK(DO_DIAG, FASTW)                                              \
    _Pragma("unroll")                                                         \
    for (int f=0; f<4; ++f){                                                  \
        float4 kn24 = *(const float4*)&kn2s[cur][f*16 + l4*4];                \
        float4 akf4 = *(const float4*)&akfs[cur][f*16 + l4*4];                \
        float4 l14  = *(const float4*)&l1s [cur][f*16 + l4*4];                \
        float wv4[4];                                                         \
        _Pragma("unroll")                                                     \
        for (int r=0; r<4; ++r){                                              \
            float sq  = fmaxf(fmaf(-2.f, c[f][r], qv + ((const float*)&kn24)[r]), 0.f); \
            float co  = fminf(aq2 * ((const float*)&akf4)[r], 2e6f);          \
            float rho = sq * co;                                              \
            float tt  = fmaf(rho, rho, rho + rho);                            \
            float zz  = 1.f + rho + __builtin_amdgcn_sqrtf(tt);               \
            float w;                                                          \
            if (FASTW){ w = __builtin_amdgcn_rcpf(zz); }                      \
            else { float L = __builtin_amdgcn_logf(zz);                       \
                   w = __builtin_amdgcn_exp2f(fmaf(-tauexp, L, gm2)); }       \
            if (DO_DIAG && (kv0 + f*16 + l4*4 + r) > qrow) w = 0.f;           \
            dn = fmaf(w, ((const float*)&l14)[r], dn);                        \
            wv4[r] = w;                                                       \
        }                                                                     \
        uint2 u2; u2.x = cvtpk(wv4[0], wv4[1]); u2.y = cvtpk(wv4[2], wv4[3]); \
        *(uint2*)&Wt[16*wv + l15][f*16 + l4*4] = u2;                          \
    }

__global__ __launch_bounds__(256,3) void k_attn(const u16t* __restrict__ Q,
        const u16t* __restrict__ K, const u16t* __restrict__ VT,
        const float* __restrict__ qn2, const float* __restrict__ kn2,
        const float* __restrict__ lam1, const float* __restrict__ taup,
        const float* __restrict__ gammap,
        float* __restrict__ pnum, float* __restrict__ pden){
    __shared__ __align__(16) u16t Kt[2][64][72];
    __shared__ __align__(16) u16t Vt[2][64][72];  // V^T tile: [d][kv]
    __shared__ __align__(16) u16t Wt[64][72];     // w[q][kv], wave-private rows
    __shared__ float kn2s[2][64], akfs[2][64], l1s[2][64];
    int bx = blockIdx.x;
    int bh = bx & 15;               // low bits -> per-bh XCD/L2 affinity
    int u = bx >> 4;                // 0..47
    int v = 47 - u;                 // heavy first
    int qi, c0;
    if (v < 16){ qi = v; c0 = 0; }
    else { qi = (v + 16) >> 1; c0 = (v + 16) & 1; }
    int jt0 = c0 << 4;
    int jt1 = min(jt0 + 16, qi + 1);
    int s0 = qi << 6;
    int tid = threadIdx.x; int wv = tid>>6; int lane = tid&63;
    int l15 = lane & 15; int l4 = lane >> 4;
    float tauexp = __expf(taup[0]);
    float gm2 = gammap[0] * 1.44269504088896340736f;  // gamma * log2(e)
    bool fastw = (tauexp == 1.0f) && (gm2 == 0.0f);
    size_t base = (size_t)bh * SS;
    int qrow = s0 + 16*wv + l15;    // this lane's global q row
    bf16x8 aQ0 = *(const bf16x8*)(Q + (base + qrow)*DD + l4*8);
    bf16x8 aQ1 = *(const bf16x8*)(Q + (base + qrow)*DD + 32 + l4*8);
    float qv  = qn2[base + qrow];
    float aq2 = 2.f * __builtin_amdgcn_rcpf(fmaxf(1.f - qv, 1e-6f));
    f32x4 z4 = {0.f,0.f,0.f,0.f};
    f32x4 num[4] = {z4,z4,z4,z4};
    float dn = 0.f;
    int rr = tid >> 2; int cc = (tid & 3) << 4;
    // register prefetch (T14)
    uint4 pka0, pka1, pva0, pva1; float pkn = 0.f, pl1 = 0.f;
    {   // prologue: load tile jt0
        int kv0 = jt0 << 6;
        const uint4* gk = (const uint4*)(K + (base + kv0 + rr)*DD + cc);
        pka0 = gk[0]; pka1 = gk[1];
        const uint4* gv = (const uint4*)(VT + ((size_t)bh*DD + rr)*SS + kv0 + cc);
        pva0 = gv[0]; pva1 = gv[1];
        if (tid < 64){ pkn = kn2[base+kv0+tid]; pl1 = lam1[base+kv0+tid]; }
    }
    int cur = 0;
    for (int jt=jt0; jt<jt1; ++jt){
        // commit prefetched tile to LDS buffer `cur` (other buffer being read)
        *(uint4*)&Kt[cur][rr][cc]   = pka0;
        *(uint4*)&Kt[cur][rr][cc+8] = pka1;
        *(uint4*)&Vt[cur][rr][cc]   = pva0;
        *(uint4*)&Vt[cur][rr][cc+8] = pva1;
        if (tid < 64){
            kn2s[cur][tid] = pkn;
            l1s[cur][tid]  = pl1;
            akfs[cur][tid] = __builtin_amdgcn_rcpf(fmaxf(1.f - pkn, 1e-6f));
        }
        __syncthreads();
        // issue next tile's global loads (overlap with compute below)
        if (jt+1 < jt1){
            int kv0n = (jt+1) << 6;
            const uint4* gk = (const uint4*)(K + (base + kv0n + rr)*DD + cc);
            pka0 = gk[0]; pka1 = gk[1];
            const uint4* gv = (const uint4*)(VT + ((size_t)bh*DD + rr)*SS + kv0n + cc);
            pva0 = gv[0]; pva1 = gv[1];
            if (tid < 64){ pkn = kn2[base+kv0n+tid]; pl1 = lam1[base+kv0n+tid]; }
        }
        int kv0 = jt << 6;
        // QK^T swapped: c[f][r] = dot(q=l15, k=16f+4l4+r)
        f32x4 c[4] = {z4,z4,z4,z4};
        #pragma unroll
        for (int f=0; f<4; ++f){
            bf16x8 kb0 = *(const bf16x8*)&Kt[cur][f*16+l15][l4*8];
            bf16x8 kb1 = *(const bf16x8*)&Kt[cur][f*16+l15][32+l4*8];
            c[f] = mfma16(kb0, aQ0, c[f]);
            c[f] = mfma16(kb1, aQ1, c[f]);
        }
        // elementwise distance -> w, packed to Wt
        if (jt == qi){
            if (fastw) { EW_BLOCK(true, true) } else { EW_BLOCK(true, false) }
        } else {
            if (fastw) { EW_BLOCK(false, true) } else { EW_BLOCK(false, false) }
        }
        // PV swapped: num[f][r] = M[q=l15][d=16f+4l4+r]
        bf16x8 pw0 = *(const bf16x8*)&Wt[16*wv + l15][l4*8];
        bf16x8 pw1 = *(const bf16x8*)&Wt[16*wv + l15][32 + l4*8];
        #pragma unroll
        for (int f=0; f<4; ++f){
            bf16x8 vb0 = *(const bf16x8*)&Vt[cur][f*16+l15][l4*8];
            bf16x8 vb1 = *(const bf16x8*)&Vt[cur][f*16+l15][32+l4*8];
            num[f] = mfma16(vb0, pw0, num[f]);
            num[f] = mfma16(vb1, pw1, num[f]);
        }
        cur ^= 1;    // next commit targets the other buffer -> no end barrier
    }
    // den: reduce over the 16 k's held per lane -> over l4 groups
    dn += __shfl_xor(dn, 16, 64);
    dn += __shfl_xor(dn, 32, 64);
    // store partials: pn[q][d] with d-consecutive float4
    size_t pidx = (size_t)bh*48 + offq16(qi) + c0;
    float* pn = pnum + pidx*4096;
    #pragma unroll
    for (int f=0; f<4; ++f)
        *(f32x4*)&pn[(16*wv + l15)*64 + f*16 + l4*4] = num[f];
    if (l4 == 0) pden[pidx*64 + 16*wv + l15] = dn;
}

// ---------------- Kernel E: combine partials + gyromidpoint + logmap + expmap --
// block = (b, 16-row s-tile); thread = (row, head, half): tid = row*16 + h*2 + half
__global__ __launch_bounds__(256) void k_post(const float* __restrict__ pnum,
        const float* __restrict__ pden, float* __restrict__ out, float beta){
    int bx = blockIdx.x;              // 2 b x 128 s-tiles
    int b = bx >> 7; int stile = bx & 127;
    int tid = threadIdx.x;
    int row = tid >> 4; int h = (tid >> 1) & 7; int half = tid & 1;
    int s = stile*16 + row;
    int qi = s >> 6; int rowin = s & 63;
    int nch = (qi >> 4) + 1;
    size_t pb = (size_t)(b*HH + h)*48 + offq16(qi);
    float mv[32];
    #pragma unroll
    for (int i=0;i<32;++i) mv[i] = 0.f;
    float den = 0.f;
    for (int cc=0; cc<nch; ++cc){
        const float* pn = pnum + (pb+cc)*4096 + rowin*64 + half*32;
        #pragma unroll
        for (int i=0;i<8;++i){
            float4 v = *(const float4*)(pn + i*4);
            mv[i*4+0]+=v.x; mv[i*4+1]+=v.y; mv[i*4+2]+=v.z; mv[i*4+3]+=v.w;
        }
        den += pden[(pb+cc)*64 + rowin];
    }
    float invd = 1.f / fmaxf(den, 1e-6f);
    float mn2h = 0.f;
    #pragma unroll
    for (int i=0;i<32;++i){ mv[i] *= invd; mn2h += mv[i]*mv[i]; }
    // per-head norm over 64 dims: pair (half) reduce
    float mn2 = mn2h + __shfl_xor(mn2h, 1, 64);
    float mn = sqrtf(fmaxf(mn2, 1e-12f));
    float g = beta * 0.5f * fast_atanh(fminf(mn, 1.0f-1e-5f)) / mn;   // t_h = g*m_h
    // E-norm^2 = sum_h g^2*mn2 : reduce over h bits (1,2,3 of tid>>1)
    float tn = g*g*mn2;
    tn += __shfl_xor(tn, 2, 64);
    tn += __shfl_xor(tn, 4, 64);
    tn += __shfl_xor(tn, 8, 64);
    float en = sqrtf(fmaxf(tn, 1e-12f));
    float f = fast_tanh(en)/en;
    float gf = g * f;
    float* dst = out + ((size_t)(b*SS + s))*EE + h*DD + half*32;
    #pragma unroll
    for (int i=0;i<8;++i){
        float4 v = {gf*mv[i*4+0], gf*mv[i*4+1], gf*mv[i*4+2], gf*mv[i*4+3]};
        *(float4*)(dst + i*4) = v;
    }
}

extern "C" void kernel_launch(void* const* d_in, const int* in_sizes, int n_in,
                              void* d_out, int out_size, void* d_ws, size_t ws_size,
                              hipStream_t stream) {
    const float* q_in  = (const float*)d_in[0];
    const float* k_in  = (const float*)d_in[1];
    const float* v_in  = (const float*)d_in[2];
    const float* Wq    = (const float*)d_in[3];
    const float* Wk    = (const float*)d_in[4];
    const float* Wv    = (const float*)d_in[5];
    const float* bq    = (const float*)d_in[6];
    const float* bk    = (const float*)d_in[7];
    const float* bv    = (const float*)d_in[8];
    const float* tau   = (const float*)d_in[9];
    const float* gamma = (const float*)d_in[10];
    float* out = (float*)d_out;

    char* ws = (char*)d_ws;
    u16t*  Tlog = (u16t*)(ws + 0);            // 12,582,912 B
    u16t*  Wb   = (u16t*)(ws + 12582912);     //  1,572,864 B
    u16t*  Ub   = (u16t*)(ws + 14155776);     // 12,582,912 B bf16
    u16t*  Qb   = (u16t*)(ws + 26738688);     //  4,194,304 B
    u16t*  Kb   = (u16t*)(ws + 30932992);     //  4,194,304 B
    u16t*  VTb  = (u16t*)(ws + 35127296);     //  4,194,304 B  (V^T * lambda)
    float* qn2  = (float*)(ws + 39321600);    //    131,072 B
    float* kn2  = (float*)(ws + 39452672);    //    131,072 B
    float* lam1 = (float*)(ws + 39583744);    //    131,072 B
    float* pnum = (float*)(ws + 39714816);    // 16*48*4096*4 = 12,582,912 B
    float* pden = (float*)(ws + 52297728);    // 16*48*64*4   =    196,608 B

    // beta-concatenation ratio: exp(lbeta(E/2,1/2) - lbeta(D/2,1/2))
    double lb1 = std::lgamma(256.0) + std::lgamma(0.5) - std::lgamma(256.5);
    double lb2 = std::lgamma(32.0)  + std::lgamma(0.5) - std::lgamma(32.5);
    float beta = (float)std::exp(lb1 - lb2);

    k_pre<<<3840, 256, 0, stream>>>(q_in, k_in, v_in, Tlog, Wq, Wk, Wv, Wb);
    k_proj<<<1536, 256, 0, stream>>>(Tlog, Wb, bq, bk, bv, Ub);
    k_expmap_split<<<3072, 256, 0, stream>>>(Ub, Qb, Kb, VTb, qn2, kn2, lam1);
    k_attn<<<768, 256, 0, stream>>>(Qb, Kb, VTb, qn2, kn2, lam1, tau, gamma,
                                    pnum, pden);
    k_post<<<256, 256, 0, stream>>>(pnum, pden, out, beta);
}

// Round 12
// 89.239 us; speedup vs baseline: 1.4898x; 1.0383x over previous
//
#include <hip/hip_runtime.h>
#include <cmath>

#define BB 2
#define SS 2048
#define EE 512
#define HH 8
#define DD 64

typedef unsigned short u16t;
typedef __bf16 bf16x8 __attribute__((ext_vector_type(8)));
typedef float f32x4 __attribute__((ext_vector_type(4)));

__device__ __forceinline__ float bf2f(u16t u){
    union{unsigned int i; float f;} c; c.i = ((unsigned int)u)<<16; return c.f;
}
__device__ __forceinline__ u16t f2bf(float x){
    union{float f; unsigned int i;} c; c.f = x;
    return (u16t)((c.i + 0x7fffu + ((c.i>>16)&1u))>>16);
}
__device__ __forceinline__ unsigned cvtpk(float a, float b){
    unsigned r;
    asm("v_cvt_pk_bf16_f32 %0, %1, %2" : "=v"(r) : "v"(a), "v"(b));
    return r;   // a -> low 16, b -> high 16 (RNE)
}
__device__ __forceinline__ float fast_tanh(float x){
    float e = __expf(2.f*x); return 1.f - 2.f/(e+1.f);
}
__device__ __forceinline__ float fast_atanh(float x){
    return 0.5f*__logf((1.f+x)/(1.f-x));
}
__device__ __forceinline__ f32x4 mfma16(bf16x8 a, bf16x8 b, f32x4 c){
    return __builtin_amdgcn_mfma_f32_16x16x32_bf16(a,b,c,0,0,0);
}
// chunk bookkeeping: QBLK=64, chunk=8 kv-tiles. qi in [0,32):
// nch(qi) = (qi>>3)+1 ; offq8(qi) = sum_{q<qi} nch(q) ; total per bh = 80
__device__ __forceinline__ int offq8(int qi){
    int a = qi >> 3;
    return 4*a*(a+1) + (qi & 7)*(a+1);
}

// ---------------- Kernel A: logmap0 rows (bf16 out) + W cvt, merged ------------
__global__ __launch_bounds__(256) void k_pre(const float* __restrict__ qp,
                                             const float* __restrict__ kp,
                                             const float* __restrict__ vp,
                                             u16t* __restrict__ Tlog,
                                             const float* __restrict__ Wq,
                                             const float* __restrict__ Wk,
                                             const float* __restrict__ Wv,
                                             u16t* __restrict__ Wb){
    int bx = blockIdx.x;
    if (bx < 3072){
        int gr = bx*4 + (threadIdx.x>>6);   // 0..12287
        int t = gr >> 12;
        int row = gr & 4095;
        int lane = threadIdx.x & 63;
        const float* src = (t==0 ? qp : (t==1 ? kp : vp)) + (size_t)row*EE;
        const float4* s4 = (const float4*)(src + lane*8);
        float4 a = s4[0], b = s4[1];
        float x[8] = {a.x,a.y,a.z,a.w,b.x,b.y,b.z,b.w};
        float p = 0.f;
        #pragma unroll
        for (int i=0;i<8;++i) p += x[i]*x[i];
        #pragma unroll
        for (int off=32; off>=1; off>>=1) p += __shfl_xor(p, off, 64);
        float n = sqrtf(fmaxf(p, 1e-12f));
        float f = fast_atanh(fminf(n, 1.0f-1e-5f)) / n;
        u16t yb[8];
        #pragma unroll
        for (int i=0;i<8;++i) yb[i] = f2bf(f*x[i]);
        uint4 o;
        o.x = (unsigned)yb[0] | ((unsigned)yb[1]<<16);
        o.y = (unsigned)yb[2] | ((unsigned)yb[3]<<16);
        o.z = (unsigned)yb[4] | ((unsigned)yb[5]<<16);
        o.w = (unsigned)yb[6] | ((unsigned)yb[7]<<16);
        *(uint4*)(Tlog + ((size_t)(t*4096+row)*EE + lane*8)) = o;
    } else {
        int idx = ((bx-3072)*256 + threadIdx.x)*4;     // 3*512*512 total
        int t = idx >> 18;
        int off = idx & 262143;
        const float* W = (t==0 ? Wq : (t==1 ? Wk : Wv));
        float4 a = *(const float4*)(W + off);
        uint2 o;
        o.x = (unsigned)f2bf(a.x) | ((unsigned)f2bf(a.y)<<16);
        o.y = (unsigned)f2bf(a.z) | ((unsigned)f2bf(a.w)<<16);
        *(uint2*)(Wb + idx) = o;
    }
}

// ---------------- Kernel B: U = Tlog @ W^T + b (MFMA GEMM, bf16 out) -----------
// Swapped operands: D = mfma(W, T) -> lane holds 4 consecutive n-cols per f
// (cvtpk + uint2 stores, float4 bias) instead of 16 scalar stores.
__global__ __launch_bounds__(256) void k_proj(const u16t* __restrict__ Tlog,
                                              const u16t* __restrict__ Wb,
                                              const float* __restrict__ bq,
                                              const float* __restrict__ bk,
                                              const float* __restrict__ bv,
                                              u16t* __restrict__ U){
    __shared__ __align__(16) u16t Wl[64][72];
    int bx = blockIdx.x;                 // 3 * 64 * 8
    int t = bx >> 9; int rem = bx & 511;
    int m0 = (rem >> 3) << 6; int n0 = (rem & 7) << 6;
    int tid = threadIdx.x; int wv = tid>>6; int lane = tid&63;
    int l15 = lane & 15; int l4 = lane >> 4;
    const u16t* Tt = Tlog + (size_t)t*4096*EE;
    const u16t* Wt = Wb + (size_t)t*EE*EE;
    const float* bias = (t==0 ? bq : (t==1 ? bk : bv));
    f32x4 z = {0.f,0.f,0.f,0.f};
    f32x4 acc[4] = {z,z,z,z};
    int arow = m0 + 16*wv + l15;
    int rr = tid >> 2; int cc = (tid & 3) * 16;
    uint4 w0, w1;
    {   // prologue: W-tile ks=0
        const uint4* g = (const uint4*)(Wt + (size_t)(n0+rr)*EE + cc);
        w0 = g[0]; w1 = g[1];
    }
    for (int ks=0; ks<8; ++ks){
        int k0 = ks*64;
        *(uint4*)&Wl[rr][cc]   = w0;
        *(uint4*)&Wl[rr][cc+8] = w1;
        __syncthreads();
        if (ks < 7){
            const uint4* g = (const uint4*)(Wt + (size_t)(n0+rr)*EE + k0 + 64 + cc);
            w0 = g[0]; w1 = g[1];
        }
        bf16x8 a0 = *(const bf16x8*)(Tt + (size_t)arow*EE + k0 + l4*8);
        bf16x8 a1 = *(const bf16x8*)(Tt + (size_t)arow*EE + k0 + 32 + l4*8);
        #pragma unroll
        for (int f=0; f<4; ++f){
            bf16x8 b0 = *(const bf16x8*)&Wl[f*16+l15][l4*8];
            bf16x8 b1 = *(const bf16x8*)&Wl[f*16+l15][32+l4*8];
            acc[f] = mfma16(b0, a0, acc[f]);   // swapped: rows=n, cols=m
            acc[f] = mfma16(b1, a1, acc[f]);
        }
        __syncthreads();
    }
    u16t* Ut = U + (size_t)t*4096*EE;
    int mrow = m0 + 16*wv + l15;
    #pragma unroll
    for (int f=0; f<4; ++f){
        float4 b4 = *(const float4*)&bias[n0 + f*16 + l4*4];
        uint2 u2;
        u2.x = cvtpk(acc[f][0]+b4.x, acc[f][1]+b4.y);
        u2.y = cvtpk(acc[f][2]+b4.z, acc[f][3]+b4.w);
        *(uint2*)(Ut + (size_t)mrow*EE + n0 + f*16 + l4*4) = u2;
    }
}

// ---------------- Kernel C: expmap0 + head split + norms (V stored transposed) --
__global__ __launch_bounds__(256) void k_expmap_split(const u16t* __restrict__ U,
        u16t* __restrict__ Q, u16t* __restrict__ K, u16t* __restrict__ VT,
        float* __restrict__ qn2, float* __restrict__ kn2, float* __restrict__ lam1){
    int gr = blockIdx.x*4 + (threadIdx.x>>6);   // 0..12287
    int t = gr >> 12;
    int row = gr & 4095;
    int b = row >> 11; int s = row & 2047;
    int lane = threadIdx.x & 63;
    const u16t* u = U + ((size_t)t*4096 + row)*EE;
    uint4 raw = *(const uint4*)(u + lane*8);
    const u16t* rs = (const u16t*)&raw;
    float x[8];
    #pragma unroll
    for (int i=0;i<8;++i) x[i] = bf2f(rs[i]);
    float p = 0.f;
    #pragma unroll
    for (int i=0;i<8;++i) p += x[i]*x[i];
    #pragma unroll
    for (int off=32; off>=1; off>>=1) p += __shfl_xor(p, off, 64);
    float n = sqrtf(fmaxf(p, 1e-12f));
    float f = fast_tanh(n)/n;
    float y[8]; u16t yb[8];
    float hp = 0.f;
    #pragma unroll
    for (int i=0;i<8;++i){
        yb[i] = f2bf(f*x[i]);
        y[i]  = bf2f(yb[i]);        // rounded values -> consistent norms
        hp += y[i]*y[i];
    }
    #pragma unroll
    for (int off=1; off<8; off<<=1) hp += __shfl_xor(hp, off, 64);
    hp = fminf(hp, 0.99999988f);    // guard: keep strictly below 1 for rcp path
    int h = lane >> 3;
    size_t ih = (size_t)(b*HH + h)*SS + s;
    if (t == 0){
        uint4 o;
        o.x=(unsigned)yb[0]|((unsigned)yb[1]<<16); o.y=(unsigned)yb[2]|((unsigned)yb[3]<<16);
        o.z=(unsigned)yb[4]|((unsigned)yb[5]<<16); o.w=(unsigned)yb[6]|((unsigned)yb[7]<<16);
        *(uint4*)(Q + ih*DD + (lane&7)*8) = o;
        if ((lane&7)==0) qn2[ih] = hp;
    } else if (t == 1){
        uint4 o;
        o.x=(unsigned)yb[0]|((unsigned)yb[1]<<16); o.y=(unsigned)yb[2]|((unsigned)yb[3]<<16);
        o.z=(unsigned)yb[4]|((unsigned)yb[5]<<16); o.w=(unsigned)yb[6]|((unsigned)yb[7]<<16);
        *(uint4*)(K + ih*DD + (lane&7)*8) = o;
        if ((lane&7)==0) kn2[ih] = hp;
    } else {
        float lam = 2.f / fmaxf(1.f - hp, 1e-6f);
        size_t bh = (size_t)(b*HH + h);
        int d0 = (lane&7)*8;
        #pragma unroll
        for (int i=0;i<8;++i)
            VT[(bh*DD + d0 + i)*SS + s] = f2bf(y[i]*lam);   // V^T, scaled by lambda
        if ((lane&7)==0) lam1[ih] = lam - 1.f;
    }
}

// ---------------- Kernel D: fused causal hyperbolic attention ------------------
// QBLK=64 (4 waves x 16q), KVBLK=64, chunk=8. Swapped-operand MFMAs; w packed
// via v_cvt_pk_bf16_f32; fast path w=rcp(zz) when tau'==1 && gamma==0 (exact:
// exp(-1*dist+0) == 1/zz), general log/exp path otherwise.
#define EW_BLOCK(DO_DIAG, FASTW)                                              \
    _Pragma("unroll")                                                         \
    for (int f=0; f<4; ++f){                                                  \
        float4 kn24 = *(const float4*)&kn2s[f*16 + l4*4];                     \
        float4 akf4 = *(const float4*)&akfs[f*16 + l4*4];                     \
        float4 l14  = *(const float4*)&l1s [f*16 + l4*4];                     \
        float wv4[4];                                                         \
        _Pragma("unroll")                                                     \
        for (int r=0; r<4; ++r){                                              \
            float sq  = fmaxf(fmaf(-2.f, c[f][r], qv + ((const float*)&kn24)[r]), 0.f); \
            float co  = fminf(aq2 * ((const float*)&akf4)[r], 2e6f);          \
            float rho = sq * co;                                              \
            float tt  = fmaf(rho, rho, rho + rho);                            \
            float zz  = 1.f + rho + __builtin_amdgcn_sqrtf(tt);               \
            float w;                                                          \
            if (FASTW){ w = __builtin_amdgcn_rcpf(zz); }                      \
            else { float L = __builtin_amdgcn_logf(zz);                       \
                   w = __builtin_amdgcn_exp2f(fmaf(-tauexp, L, gm2)); }       \
            if (DO_DIAG && (kv0 + f*16 + l4*4 + r) > qrow) w = 0.f;           \
            dn = fmaf(w, ((const float*)&l14)[r], dn);                        \
            wv4[r] = w;                                                       \
        }                                                                     \
        uint2 u2; u2.x = cvtpk(wv4[0], wv4[1]); u2.y = cvtpk(wv4[2], wv4[3]); \
        *(uint2*)&Wt[16*wv + l15][f*16 + l4*4] = u2;                          \
    }

__global__ __launch_bounds__(256,5) void k_attn(const u16t* __restrict__ Q,
        const u16t* __restrict__ K, const u16t* __restrict__ VT,
        const float* __restrict__ qn2, const float* __restrict__ kn2,
        const float* __restrict__ lam1, const float* __restrict__ taup,
        const float* __restrict__ gammap,
        float* __restrict__ pnum, float* __restrict__ pden){
    __shared__ __align__(16) u16t Kt[64][72];
    __shared__ __align__(16) u16t Vt[64][72];   // V^T tile: [d][kv]
    __shared__ __align__(16) u16t Wt[64][72];   // w[q][kv], per-wave row stripes
    __shared__ float kn2s[64], akfs[64], l1s[64];
    int bx = blockIdx.x;
    int bh = bx & 15;               // low bits -> per-bh XCD/L2 affinity
    int u = bx >> 4;                // 0..79
    int v = 79 - u;                 // heavy qi first
    int qi = 31;
    while (offq8(qi) > v) --qi;
    int c0 = v - offq8(qi);
    int jt0 = c0 << 3;
    int jt1 = min(jt0 + 8, qi + 1);
    int s0 = qi << 6;
    int tid = threadIdx.x; int wv = tid>>6; int lane = tid&63;
    int l15 = lane & 15; int l4 = lane >> 4;
    float tauexp = __expf(taup[0]);
    float gm2 = gammap[0] * 1.44269504088896340736f;  // gamma * log2(e)
    bool fastw = (tauexp == 1.0f) && (gm2 == 0.0f);
    size_t base = (size_t)bh * SS;
    int qrow = s0 + 16*wv + l15;    // this lane's global q row
    bf16x8 aQ0 = *(const bf16x8*)(Q + (base + qrow)*DD + l4*8);
    bf16x8 aQ1 = *(const bf16x8*)(Q + (base + qrow)*DD + 32 + l4*8);
    float qv  = qn2[base + qrow];
    float aq2 = 2.f * __builtin_amdgcn_rcpf(fmaxf(1.f - qv, 1e-6f));
    f32x4 z4 = {0.f,0.f,0.f,0.f};
    f32x4 num[4] = {z4,z4,z4,z4};
    float dn = 0.f;
    int rr = tid >> 2; int cc = (tid & 3) << 4;
    // register prefetch (T14)
    uint4 pka0, pka1, pva0, pva1; float pkn = 0.f, pl1 = 0.f;
    {   // prologue: load tile jt0
        int kv0 = jt0 << 6;
        const uint4* gk = (const uint4*)(K + (base + kv0 + rr)*DD + cc);
        pka0 = gk[0]; pka1 = gk[1];
        const uint4* gv = (const uint4*)(VT + ((size_t)bh*DD + rr)*SS + kv0 + cc);
        pva0 = gv[0]; pva1 = gv[1];
        if (tid < 64){ pkn = kn2[base+kv0+tid]; pl1 = lam1[base+kv0+tid]; }
    }
    for (int jt=jt0; jt<jt1; ++jt){
        // commit prefetched tile to LDS
        *(uint4*)&Kt[rr][cc]   = pka0;
        *(uint4*)&Kt[rr][cc+8] = pka1;
        *(uint4*)&Vt[rr][cc]   = pva0;
        *(uint4*)&Vt[rr][cc+8] = pva1;
        if (tid < 64){
            kn2s[tid] = pkn;
            l1s[tid]  = pl1;
            akfs[tid] = __builtin_amdgcn_rcpf(fmaxf(1.f - pkn, 1e-6f));
        }
        __syncthreads();
        // issue next tile's global loads (overlap with compute below)
        if (jt+1 < jt1){
            int kv0n = (jt+1) << 6;
            const uint4* gk = (const uint4*)(K + (base + kv0n + rr)*DD + cc);
            pka0 = gk[0]; pka1 = gk[1];
            const uint4* gv = (const uint4*)(VT + ((size_t)bh*DD + rr)*SS + kv0n + cc);
            pva0 = gv[0]; pva1 = gv[1];
            if (tid < 64){ pkn = kn2[base+kv0n+tid]; pl1 = lam1[base+kv0n+tid]; }
        }
        int kv0 = jt << 6;
        // QK^T swapped: c[f][r] = dot(q=l15, k=16f+4l4+r)
        f32x4 c[4] = {z4,z4,z4,z4};
        #pragma unroll
        for (int f=0; f<4; ++f){
            bf16x8 kb0 = *(const bf16x8*)&Kt[f*16+l15][l4*8];
            bf16x8 kb1 = *(const bf16x8*)&Kt[f*16+l15][32+l4*8];
            c[f] = mfma16(kb0, aQ0, c[f]);
            c[f] = mfma16(kb1, aQ1, c[f]);
        }
        // elementwise distance -> w, packed to Wt
        if (jt == qi){
            if (fastw) { EW_BLOCK(true, true) } else { EW_BLOCK(true, false) }
        } else {
            if (fastw) { EW_BLOCK(false, true) } else { EW_BLOCK(false, false) }
        }
        // PV swapped: num[f][r] = M[q=l15][d=16f+4l4+r]
        bf16x8 pw0 = *(const bf16x8*)&Wt[16*wv + l15][l4*8];
        bf16x8 pw1 = *(const bf16x8*)&Wt[16*wv + l15][32 + l4*8];
        #pragma unroll
        for (int f=0; f<4; ++f){
            bf16x8 vb0 = *(const bf16x8*)&Vt[f*16+l15][l4*8];
            bf16x8 vb1 = *(const bf16x8*)&Vt[f*16+l15][32+l4*8];
            num[f] = mfma16(vb0, pw0, num[f]);
            num[f] = mfma16(vb1, pw1, num[f]);
        }
        __syncthreads();
    }
    // den: reduce over the 16 k's held per lane -> over l4 groups
    dn += __shfl_xor(dn, 16, 64);
    dn += __shfl_xor(dn, 32, 64);
    // store partials: pn[q][d] with d-consecutive float4
    size_t pidx = (size_t)bh*80 + offq8(qi) + c0;
    float* pn = pnum + pidx*4096;
    #pragma unroll
    for (int f=0; f<4; ++f)
        *(f32x4*)&pn[(16*wv + l15)*64 + f*16 + l4*4] = num[f];
    if (l4 == 0) pden[pidx*64 + 16*wv + l15] = dn;
}

// ---------------- Kernel E: combine partials + gyromidpoint + logmap + expmap --
// Re-gridded for occupancy: 1024 blocks (2b x 512 four-row s-tiles);
// thread = row(4) x head(8) x oct(8 cols). All reductions in-wave:
// oct = lane bits 0-2 (xor 1,2,4), heads = lane bits 3-5 (xor 8,16,32).
__global__ __launch_bounds__(256) void k_post(const float* __restrict__ pnum,
        const float* __restrict__ pden, float* __restrict__ out, float beta){
    int bx = blockIdx.x;              // 2 b x 512 s-tiles (4 rows each)
    int b = bx >> 9; int stile = bx & 511;
    int tid = threadIdx.x;
    int row = tid >> 6;               // wave index = row in tile
    int h = (tid >> 3) & 7; int oct = tid & 7;
    int s = stile*4 + row;
    int qi = s >> 6; int rowin = s & 63;
    int nch = (qi >> 3) + 1;
    size_t pb = (size_t)(b*HH + h)*80 + offq8(qi);
    float mv[8];
    #pragma unroll
    for (int i=0;i<8;++i) mv[i] = 0.f;
    float den = 0.f;
    for (int cc=0; cc<nch; ++cc){
        const float* pn = pnum + (pb+cc)*4096 + rowin*64 + oct*8;
        float4 v0 = *(const float4*)(pn);
        float4 v1 = *(const float4*)(pn + 4);
        mv[0]+=v0.x; mv[1]+=v0.y; mv[2]+=v0.z; mv[3]+=v0.w;
        mv[4]+=v1.x; mv[5]+=v1.y; mv[6]+=v1.z; mv[7]+=v1.w;
        den += pden[(pb+cc)*64 + rowin];
    }
    float invd = 1.f / fmaxf(den, 1e-6f);
    float mn2o = 0.f;
    #pragma unroll
    for (int i=0;i<8;++i){ mv[i] *= invd; mn2o += mv[i]*mv[i]; }
    // per-head norm over 64 dims: reduce over oct lanes (bits 0-2)
    float mn2 = mn2o;
    mn2 += __shfl_xor(mn2, 1, 64);
    mn2 += __shfl_xor(mn2, 2, 64);
    mn2 += __shfl_xor(mn2, 4, 64);
    float mn = sqrtf(fmaxf(mn2, 1e-12f));
    float g = beta * 0.5f * fast_atanh(fminf(mn, 1.0f-1e-5f)) / mn;   // t_h = g*m_h
    // E-norm^2 = sum_h g^2*mn2 : reduce over head lanes (bits 3-5)
    float tn = g*g*mn2;
    tn += __shfl_xor(tn, 8, 64);
    tn += __shfl_xor(tn, 16, 64);
    tn += __shfl_xor(tn, 32, 64);
    float en = sqrtf(fmaxf(tn, 1e-12f));
    float f = fast_tanh(en)/en;
    float gf = g * f;
    float* dst = out + ((size_t)(b*SS + s))*EE + h*DD + oct*8;
    float4 o0 = {gf*mv[0], gf*mv[1], gf*mv[2], gf*mv[3]};
    float4 o1 = {gf*mv[4], gf*mv[5], gf*mv[6], gf*mv[7]};
    *(float4*)(dst)     = o0;
    *(float4*)(dst + 4) = o1;
}

extern "C" void kernel_launch(void* const* d_in, const int* in_sizes, int n_in,
                              void* d_out, int out_size, void* d_ws, size_t ws_size,
                              hipStream_t stream) {
    const float* q_in  = (const float*)d_in[0];
    const float* k_in  = (const float*)d_in[1];
    const float* v_in  = (const float*)d_in[2];
    const float* Wq    = (const float*)d_in[3];
    const float* Wk    = (const float*)d_in[4];
    const float* Wv    = (const float*)d_in[5];
    const float* bq    = (const float*)d_in[6];
    const float* bk    = (const float*)d_in[7];
    const float* bv    = (const float*)d_in[8];
    const float* tau   = (const float*)d_in[9];
    const float* gamma = (const float*)d_in[10];
    float* out = (float*)d_out;

    char* ws = (char*)d_ws;
    u16t*  Tlog = (u16t*)(ws + 0);            // 12,582,912 B
    u16t*  Wb   = (u16t*)(ws + 12582912);     //  1,572,864 B
    u16t*  Ub   = (u16t*)(ws + 14155776);     // 12,582,912 B bf16
    u16t*  Qb   = (u16t*)(ws + 26738688);     //  4,194,304 B
    u16t*  Kb   = (u16t*)(ws + 30932992);     //  4,194,304 B
    u16t*  VTb  = (u16t*)(ws + 35127296);     //  4,194,304 B  (V^T * lambda)
    float* qn2  = (float*)(ws + 39321600);    //    131,072 B
    float* kn2  = (float*)(ws + 39452672);    //    131,072 B
    float* lam1 = (float*)(ws + 39583744);    //    131,072 B
    float* pnum = (float*)(ws + 39714816);    // 16*80*4096*4 = 20,971,520 B
    float* pden = (float*)(ws + 60686336);    // 16*80*64*4   =    327,680 B

    // beta-concatenation ratio: exp(lbeta(E/2,1/2) - lbeta(D/2,1/2))
    double lb1 = std::lgamma(256.0) + std::lgamma(0.5) - std::lgamma(256.5);
    double lb2 = std::lgamma(32.0)  + std::lgamma(0.5) - std::lgamma(32.5);
    float beta = (float)std::exp(lb1 - lb2);

    k_pre<<<3840, 256, 0, stream>>>(q_in, k_in, v_in, Tlog, Wq, Wk, Wv, Wb);
    k_proj<<<1536, 256, 0, stream>>>(Tlog, Wb, bq, bk, bv, Ub);
    k_expmap_split<<<3072, 256, 0, stream>>>(Ub, Qb, Kb, VTb, qn2, kn2, lam1);
    k_attn<<<1280, 256, 0, stream>>>(Qb, Kb, VTb, qn2, kn2, lam1, tau, gamma,
                                     pnum, pden);
    k_post<<<1024, 256, 0, stream>>>(pnum, pden, out, beta);
}

// Round 13
// 80.492 us; speedup vs baseline: 1.6518x; 1.1087x over previous
//
#include <hip/hip_runtime.h>
#include <cmath>

#define BB 2
#define SS 2048
#define EE 512
#define HH 8
#define DD 64

typedef unsigned short u16t;
typedef __bf16 bf16x8 __attribute__((ext_vector_type(8)));
typedef float f32x4 __attribute__((ext_vector_type(4)));

__device__ __forceinline__ float bf2f(u16t u){
    union{unsigned int i; float f;} c; c.i = ((unsigned int)u)<<16; return c.f;
}
__device__ __forceinline__ u16t f2bf(float x){
    union{float f; unsigned int i;} c; c.f = x;
    return (u16t)((c.i + 0x7fffu + ((c.i>>16)&1u))>>16);
}
__device__ __forceinline__ unsigned cvtpk(float a, float b){
    unsigned r;
    asm("v_cvt_pk_bf16_f32 %0, %1, %2" : "=v"(r) : "v"(a), "v"(b));
    return r;   // a -> low 16, b -> high 16 (RNE)
}
__device__ __forceinline__ float fast_tanh(float x){
    float e = __expf(2.f*x); return 1.f - 2.f/(e+1.f);
}
__device__ __forceinline__ float fast_atanh(float x){
    return 0.5f*__logf((1.f+x)/(1.f-x));
}
__device__ __forceinline__ f32x4 mfma16(bf16x8 a, bf16x8 b, f32x4 c){
    return __builtin_amdgcn_mfma_f32_16x16x32_bf16(a,b,c,0,0,0);
}
// chunk bookkeeping: QBLK=64, chunk=8 kv-tiles. qi in [0,32):
// nch(qi) = (qi>>3)+1 ; offq8(qi) = sum_{q<qi} nch(q) ; total per bh = 80
__device__ __forceinline__ int offq8(int qi){
    int a = qi >> 3;
    return 4*a*(a+1) + (qi & 7)*(a+1);
}

// ---------------- Kernel A: logmap0 rows (bf16 out) + W cvt, merged ------------
__global__ __launch_bounds__(256) void k_pre(const float* __restrict__ qp,
                                             const float* __restrict__ kp,
                                             const float* __restrict__ vp,
                                             u16t* __restrict__ Tlog,
                                             const float* __restrict__ Wq,
                                             const float* __restrict__ Wk,
                                             const float* __restrict__ Wv,
                                             u16t* __restrict__ Wb){
    int bx = blockIdx.x;
    if (bx < 3072){
        int gr = bx*4 + (threadIdx.x>>6);   // 0..12287
        int t = gr >> 12;
        int row = gr & 4095;
        int lane = threadIdx.x & 63;
        const float* src = (t==0 ? qp : (t==1 ? kp : vp)) + (size_t)row*EE;
        const float4* s4 = (const float4*)(src + lane*8);
        float4 a = s4[0], b = s4[1];
        float x[8] = {a.x,a.y,a.z,a.w,b.x,b.y,b.z,b.w};
        float p = 0.f;
        #pragma unroll
        for (int i=0;i<8;++i) p += x[i]*x[i];
        #pragma unroll
        for (int off=32; off>=1; off>>=1) p += __shfl_xor(p, off, 64);
        float n = sqrtf(fmaxf(p, 1e-12f));
        float f = fast_atanh(fminf(n, 1.0f-1e-5f)) / n;
        u16t yb[8];
        #pragma unroll
        for (int i=0;i<8;++i) yb[i] = f2bf(f*x[i]);
        uint4 o;
        o.x = (unsigned)yb[0] | ((unsigned)yb[1]<<16);
        o.y = (unsigned)yb[2] | ((unsigned)yb[3]<<16);
        o.z = (unsigned)yb[4] | ((unsigned)yb[5]<<16);
        o.w = (unsigned)yb[6] | ((unsigned)yb[7]<<16);
        *(uint4*)(Tlog + ((size_t)(t*4096+row)*EE + lane*8)) = o;
    } else {
        int idx = ((bx-3072)*256 + threadIdx.x)*4;     // 3*512*512 total
        int t = idx >> 18;
        int off = idx & 262143;
        const float* W = (t==0 ? Wq : (t==1 ? Wk : Wv));
        float4 a = *(const float4*)(W + off);
        uint2 o;
        o.x = (unsigned)f2bf(a.x) | ((unsigned)f2bf(a.y)<<16);
        o.y = (unsigned)f2bf(a.z) | ((unsigned)f2bf(a.w)<<16);
        *(uint2*)(Wb + idx) = o;
    }
}

// ---------------- Kernel B: U = Tlog @ W^T + b (MFMA GEMM, bf16 out) -----------
// XCD-aware block order: m in LOW bits of rem -> the 8 n-blocks sharing one
// A-row-panel have bids 64 apart (== same XCD slot) so A re-reads hit that
// XCD's L2 instead of bouncing through L3/HBM (round-10/12 lesson).
__global__ __launch_bounds__(256) void k_proj(const u16t* __restrict__ Tlog,
                                              const u16t* __restrict__ Wb,
                                              const float* __restrict__ bq,
                                              const float* __restrict__ bk,
                                              const float* __restrict__ bv,
                                              u16t* __restrict__ U){
    __shared__ __align__(16) u16t Wl[64][72];
    int bx = blockIdx.x;                 // 3 * 64 * 8
    int t = bx >> 9; int rem = bx & 511;
    int m0 = (rem & 63) << 6; int n0 = (rem >> 6) << 6;
    int tid = threadIdx.x; int wv = tid>>6; int lane = tid&63;
    int l15 = lane & 15; int l4 = lane >> 4;
    const u16t* Tt = Tlog + (size_t)t*4096*EE;
    const u16t* Wt = Wb + (size_t)t*EE*EE;
    const float* bias = (t==0 ? bq : (t==1 ? bk : bv));
    f32x4 z = {0.f,0.f,0.f,0.f};
    f32x4 acc[4] = {z,z,z,z};
    int arow = m0 + 16*wv + l15;
    int rr = tid >> 2; int cc = (tid & 3) * 16;
    uint4 w0, w1;
    {   // prologue: W-tile ks=0
        const uint4* g = (const uint4*)(Wt + (size_t)(n0+rr)*EE + cc);
        w0 = g[0]; w1 = g[1];
    }
    for (int ks=0; ks<8; ++ks){
        int k0 = ks*64;
        *(uint4*)&Wl[rr][cc]   = w0;
        *(uint4*)&Wl[rr][cc+8] = w1;
        __syncthreads();
        if (ks < 7){
            const uint4* g = (const uint4*)(Wt + (size_t)(n0+rr)*EE + k0 + 64 + cc);
            w0 = g[0]; w1 = g[1];
        }
        bf16x8 a0 = *(const bf16x8*)(Tt + (size_t)arow*EE + k0 + l4*8);
        bf16x8 a1 = *(const bf16x8*)(Tt + (size_t)arow*EE + k0 + 32 + l4*8);
        #pragma unroll
        for (int f=0; f<4; ++f){
            bf16x8 b0 = *(const bf16x8*)&Wl[f*16+l15][l4*8];
            bf16x8 b1 = *(const bf16x8*)&Wl[f*16+l15][32+l4*8];
            acc[f] = mfma16(b0, a0, acc[f]);   // swapped: rows=n, cols=m
            acc[f] = mfma16(b1, a1, acc[f]);
        }
        __syncthreads();
    }
    u16t* Ut = U + (size_t)t*4096*EE;
    int mrow = m0 + 16*wv + l15;
    #pragma unroll
    for (int f=0; f<4; ++f){
        float4 b4 = *(const float4*)&bias[n0 + f*16 + l4*4];
        uint2 u2;
        u2.x = cvtpk(acc[f][0]+b4.x, acc[f][1]+b4.y);
        u2.y = cvtpk(acc[f][2]+b4.z, acc[f][3]+b4.w);
        *(uint2*)(Ut + (size_t)mrow*EE + n0 + f*16 + l4*4) = u2;
    }
}

// ---------------- Kernel C: expmap0 + head split + norms ------------------------
// t=0/1 (Q,K): 4-row blocks, coalesced row writes (as before).
// t=2 (V): 16-row blocks; V^T*lambda tile assembled in LDS (conflict-free
// uint4 writes), then written as 32-B aligned chunks per VT row -- replaces
// the old 2-byte global scatter (64 cache lines per store instruction).
__global__ __launch_bounds__(256) void k_expmap_split(const u16t* __restrict__ U,
        u16t* __restrict__ Q, u16t* __restrict__ K, u16t* __restrict__ VT,
        float* __restrict__ qn2, float* __restrict__ kn2, float* __restrict__ lam1){
    __shared__ __align__(16) u16t vt2[16][520];   // [s-off][h*64+d], pad 520
    int bx = blockIdx.x;
    int tid = threadIdx.x;
    int wvi = tid >> 6; int lane = tid & 63;
    if (bx < 2048){
        int gr = bx*4 + wvi;            // rows 0..8191 -> t in {0,1}
        int t = gr >> 12;
        int row = gr & 4095;
        int b = row >> 11; int s = row & 2047;
        const u16t* u = U + ((size_t)t*4096 + row)*EE;
        uint4 raw = *(const uint4*)(u + lane*8);
        const u16t* rs = (const u16t*)&raw;
        float x[8];
        #pragma unroll
        for (int i=0;i<8;++i) x[i] = bf2f(rs[i]);
        float p = 0.f;
        #pragma unroll
        for (int i=0;i<8;++i) p += x[i]*x[i];
        #pragma unroll
        for (int off=32; off>=1; off>>=1) p += __shfl_xor(p, off, 64);
        float n = sqrtf(fmaxf(p, 1e-12f));
        float f = fast_tanh(n)/n;
        u16t yb[8];
        float hp = 0.f;
        #pragma unroll
        for (int i=0;i<8;++i){
            yb[i] = f2bf(f*x[i]);
            float yr = bf2f(yb[i]);
            hp += yr*yr;
        }
        #pragma unroll
        for (int off=1; off<8; off<<=1) hp += __shfl_xor(hp, off, 64);
        hp = fminf(hp, 0.99999988f);
        int h = lane >> 3;
        size_t ih = (size_t)(b*HH + h)*SS + s;
        uint4 o;
        o.x=(unsigned)yb[0]|((unsigned)yb[1]<<16); o.y=(unsigned)yb[2]|((unsigned)yb[3]<<16);
        o.z=(unsigned)yb[4]|((unsigned)yb[5]<<16); o.w=(unsigned)yb[6]|((unsigned)yb[7]<<16);
        if (t == 0){
            *(uint4*)(Q + ih*DD + (lane&7)*8) = o;
            if ((lane&7)==0) qn2[ih] = hp;
        } else {
            *(uint4*)(K + ih*DD + (lane&7)*8) = o;
            if ((lane&7)==0) kn2[ih] = hp;
        }
    } else {
        int bx2 = bx - 2048;            // 0..255, 16 v-rows each
        int r0 = bx2 * 16;
        int b = r0 >> 11; int s0 = r0 & 2047;
        for (int p4 = 0; p4 < 4; ++p4){
            int rloc = p4*4 + wvi;      // 0..15
            int row = r0 + rloc;
            int s = s0 + rloc;
            const u16t* u = U + ((size_t)2*4096 + row)*EE;
            uint4 raw = *(const uint4*)(u + lane*8);
            const u16t* rs = (const u16t*)&raw;
            float x[8];
            #pragma unroll
            for (int i=0;i<8;++i) x[i] = bf2f(rs[i]);
            float p = 0.f;
            #pragma unroll
            for (int i=0;i<8;++i) p += x[i]*x[i];
            #pragma unroll
            for (int off=32; off>=1; off>>=1) p += __shfl_xor(p, off, 64);
            float n = sqrtf(fmaxf(p, 1e-12f));
            float f = fast_tanh(n)/n;
            u16t yb[8]; float y[8];
            float hp = 0.f;
            #pragma unroll
            for (int i=0;i<8;++i){
                yb[i] = f2bf(f*x[i]);
                y[i]  = bf2f(yb[i]);
                hp += y[i]*y[i];
            }
            #pragma unroll
            for (int off=1; off<8; off<<=1) hp += __shfl_xor(hp, off, 64);
            hp = fminf(hp, 0.99999988f);
            float lam = 2.f / fmaxf(1.f - hp, 1e-6f);
            u16t vb[8];
            #pragma unroll
            for (int i=0;i<8;++i) vb[i] = f2bf(y[i]*lam);
            uint4 o;
            o.x=(unsigned)vb[0]|((unsigned)vb[1]<<16); o.y=(unsigned)vb[2]|((unsigned)vb[3]<<16);
            o.z=(unsigned)vb[4]|((unsigned)vb[5]<<16); o.w=(unsigned)vb[6]|((unsigned)vb[7]<<16);
            *(uint4*)&vt2[rloc][lane*8] = o;     // contiguous 16B -> conflict-free
            if ((lane&7)==0){
                int h = lane >> 3;
                lam1[(size_t)(b*HH + h)*SS + s] = lam - 1.f;
            }
        }
        __syncthreads();
        // writeout: thread handles 2 VT rows (h*64+d), 16 cols = 32 B each
        #pragma unroll
        for (int q=0; q<2; ++q){
            int rp = tid*2 + q;         // 0..511
            u16t tmp[16];
            #pragma unroll
            for (int c=0; c<16; ++c) tmp[c] = vt2[c][rp];
            uint4 o0, o1;
            o0.x=(unsigned)tmp[0]|((unsigned)tmp[1]<<16);  o0.y=(unsigned)tmp[2]|((unsigned)tmp[3]<<16);
            o0.z=(unsigned)tmp[4]|((unsigned)tmp[5]<<16);  o0.w=(unsigned)tmp[6]|((unsigned)tmp[7]<<16);
            o1.x=(unsigned)tmp[8]|((unsigned)tmp[9]<<16);  o1.y=(unsigned)tmp[10]|((unsigned)tmp[11]<<16);
            o1.z=(unsigned)tmp[12]|((unsigned)tmp[13]<<16);o1.w=(unsigned)tmp[14]|((unsigned)tmp[15]<<16);
            u16t* dst = VT + ((size_t)(b*512 + rp))*SS + s0;
            *(uint4*)(dst)     = o0;
            *(uint4*)(dst + 8) = o1;
        }
    }
}

// ---------------- Kernel D: fused causal hyperbolic attention ------------------
// QBLK=64 (4 waves x 16q), KVBLK=64, chunk=8. Swapped-operand MFMAs; w packed
// via v_cvt_pk_bf16_f32; fast path w=rcp(zz) when tau'==1 && gamma==0 (exact:
// exp(-1*dist+0) == 1/zz), general log/exp path otherwise.
#define EW_BLOCK(DO_DIAG, FASTW)                                              \
    _Pragma("unroll")                                                         \
    for (int f=0; f<4; ++f){                                                  \
        float4 kn24 = *(const float4*)&kn2s[f*16 + l4*4];                     \
        float4 akf4 = *(const float4*)&akfs[f*16 + l4*4];                     \
        float4 l14  = *(const float4*)&l1s [f*16 + l4*4];                     \
        float wv4[4];                                                         \
        _Pragma("unroll")                                                     \
        for (int r=0; r<4; ++r){                                              \
            float sq  = fmaxf(fmaf(-2.f, c[f][r], qv + ((const float*)&kn24)[r]), 0.f); \
            float co  = fminf(aq2 * ((const float*)&akf4)[r], 2e6f);          \
            float rho = sq * co;                                              \
            float tt  = fmaf(rho, rho, rho + rho);                            \
            float zz  = 1.f + rho + __builtin_amdgcn_sqrtf(tt);               \
            float w;                                                          \
            if (FASTW){ w = __builtin_amdgcn_rcpf(zz); }                      \
            else { float L = __builtin_amdgcn_logf(zz);                       \
                   w = __builtin_amdgcn_exp2f(fmaf(-tauexp, L, gm2)); }       \
            if (DO_DIAG && (kv0 + f*16 + l4*4 + r) > qrow) w = 0.f;           \
            dn = fmaf(w, ((const float*)&l14)[r], dn);                        \
            wv4[r] = w;                                                       \
        }                                                                     \
        uint2 u2; u2.x = cvtpk(wv4[0], wv4[1]); u2.y = cvtpk(wv4[2], wv4[3]); \
        *(uint2*)&Wt[16*wv + l15][f*16 + l4*4] = u2;                          \
    }

__global__ __launch_bounds__(256,5) void k_attn(const u16t* __restrict__ Q,
        const u16t* __restrict__ K, const u16t* __restrict__ VT,
        const float* __restrict__ qn2, const float* __restrict__ kn2,
        const float* __restrict__ lam1, const float* __restrict__ taup,
        const float* __restrict__ gammap,
        float* __restrict__ pnum, float* __restrict__ pden){
    __shared__ __align__(16) u16t Kt[64][72];
    __shared__ __align__(16) u16t Vt[64][72];   // V^T tile: [d][kv]
    __shared__ __align__(16) u16t Wt[64][72];   // w[q][kv], per-wave row stripes
    __shared__ float kn2s[64], akfs[64], l1s[64];
    int bx = blockIdx.x;
    int bh = bx & 15;               // low bits -> per-bh XCD/L2 affinity
    int u = bx >> 4;                // 0..79
    int v = 79 - u;                 // heavy qi first
    int qi = 31;
    while (offq8(qi) > v) --qi;
    int c0 = v - offq8(qi);
    int jt0 = c0 << 3;
    int jt1 = min(jt0 + 8, qi + 1);
    int s0 = qi << 6;
    int tid = threadIdx.x; int wv = tid>>6; int lane = tid&63;
    int l15 = lane & 15; int l4 = lane >> 4;
    float tauexp = __expf(taup[0]);
    float gm2 = gammap[0] * 1.44269504088896340736f;  // gamma * log2(e)
    bool fastw = (tauexp == 1.0f) && (gm2 == 0.0f);
    size_t base = (size_t)bh * SS;
    int qrow = s0 + 16*wv + l15;    // this lane's global q row
    bf16x8 aQ0 = *(const bf16x8*)(Q + (base + qrow)*DD + l4*8);
    bf16x8 aQ1 = *(const bf16x8*)(Q + (base + qrow)*DD + 32 + l4*8);
    float qv  = qn2[base + qrow];
    float aq2 = 2.f * __builtin_amdgcn_rcpf(fmaxf(1.f - qv, 1e-6f));
    f32x4 z4 = {0.f,0.f,0.f,0.f};
    f32x4 num[4] = {z4,z4,z4,z4};
    float dn = 0.f;
    int rr = tid >> 2; int cc = (tid & 3) << 4;
    // register prefetch (T14)
    uint4 pka0, pka1, pva0, pva1; float pkn = 0.f, pl1 = 0.f;
    {   // prologue: load tile jt0
        int kv0 = jt0 << 6;
        const uint4* gk = (const uint4*)(K + (base + kv0 + rr)*DD + cc);
        pka0 = gk[0]; pka1 = gk[1];
        const uint4* gv = (const uint4*)(VT + ((size_t)bh*DD + rr)*SS + kv0 + cc);
        pva0 = gv[0]; pva1 = gv[1];
        if (tid < 64){ pkn = kn2[base+kv0+tid]; pl1 = lam1[base+kv0+tid]; }
    }
    for (int jt=jt0; jt<jt1; ++jt){
        // commit prefetched tile to LDS
        *(uint4*)&Kt[rr][cc]   = pka0;
        *(uint4*)&Kt[rr][cc+8] = pka1;
        *(uint4*)&Vt[rr][cc]   = pva0;
        *(uint4*)&Vt[rr][cc+8] = pva1;
        if (tid < 64){
            kn2s[tid] = pkn;
            l1s[tid]  = pl1;
            akfs[tid] = __builtin_amdgcn_rcpf(fmaxf(1.f - pkn, 1e-6f));
        }
        __syncthreads();
        // issue next tile's global loads (overlap with compute below)
        if (jt+1 < jt1){
            int kv0n = (jt+1) << 6;
            const uint4* gk = (const uint4*)(K + (base + kv0n + rr)*DD + cc);
            pka0 = gk[0]; pka1 = gk[1];
            const uint4* gv = (const uint4*)(VT + ((size_t)bh*DD + rr)*SS + kv0n + cc);
            pva0 = gv[0]; pva1 = gv[1];
            if (tid < 64){ pkn = kn2[base+kv0n+tid]; pl1 = lam1[base+kv0n+tid]; }
        }
        int kv0 = jt << 6;
        // QK^T swapped: c[f][r] = dot(q=l15, k=16f+4l4+r)
        f32x4 c[4] = {z4,z4,z4,z4};
        #pragma unroll
        for (int f=0; f<4; ++f){
            bf16x8 kb0 = *(const bf16x8*)&Kt[f*16+l15][l4*8];
            bf16x8 kb1 = *(const bf16x8*)&Kt[f*16+l15][32+l4*8];
            c[f] = mfma16(kb0, aQ0, c[f]);
            c[f] = mfma16(kb1, aQ1, c[f]);
        }
        // elementwise distance -> w, packed to Wt
        if (jt == qi){
            if (fastw) { EW_BLOCK(true, true) } else { EW_BLOCK(true, false) }
        } else {
            if (fastw) { EW_BLOCK(false, true) } else { EW_BLOCK(false, false) }
        }
        // PV swapped: num[f][r] = M[q=l15][d=16f+4l4+r]
        bf16x8 pw0 = *(const bf16x8*)&Wt[16*wv + l15][l4*8];
        bf16x8 pw1 = *(const bf16x8*)&Wt[16*wv + l15][32 + l4*8];
        #pragma unroll
        for (int f=0; f<4; ++f){
            bf16x8 vb0 = *(const bf16x8*)&Vt[f*16+l15][l4*8];
            bf16x8 vb1 = *(const bf16x8*)&Vt[f*16+l15][32+l4*8];
            num[f] = mfma16(vb0, pw0, num[f]);
            num[f] = mfma16(vb1, pw1, num[f]);
        }
        __syncthreads();
    }
    // den: reduce over the 16 k's held per lane -> over l4 groups
    dn += __shfl_xor(dn, 16, 64);
    dn += __shfl_xor(dn, 32, 64);
    // store partials: pn[q][d] with d-consecutive float4
    size_t pidx = (size_t)bh*80 + offq8(qi) + c0;
    float* pn = pnum + pidx*4096;
    #pragma unroll
    for (int f=0; f<4; ++f)
        *(f32x4*)&pn[(16*wv + l15)*64 + f*16 + l4*4] = num[f];
    if (l4 == 0) pden[pidx*64 + 16*wv + l15] = dn;
}

// ---------------- Kernel E: combine partials + gyromidpoint + logmap + expmap --
// 1024 blocks (2b x 512 four-row s-tiles); thread = row(4) x head(8) x oct(8).
__global__ __launch_bounds__(256) void k_post(const float* __restrict__ pnum,
        const float* __restrict__ pden, float* __restrict__ out, float beta){
    int bx = blockIdx.x;              // 2 b x 512 s-tiles (4 rows each)
    int b = bx >> 9; int stile = bx & 511;
    int tid = threadIdx.x;
    int row = tid >> 6;               // wave index = row in tile
    int h = (tid >> 3) & 7; int oct = tid & 7;
    int s = stile*4 + row;
    int qi = s >> 6; int rowin = s & 63;
    int nch = (qi >> 3) + 1;
    size_t pb = (size_t)(b*HH + h)*80 + offq8(qi);
    float mv[8];
    #pragma unroll
    for (int i=0;i<8;++i) mv[i] = 0.f;
    float den = 0.f;
    for (int cc=0; cc<nch; ++cc){
        const float* pn = pnum + (pb+cc)*4096 + rowin*64 + oct*8;
        float4 v0 = *(const float4*)(pn);
        float4 v1 = *(const float4*)(pn + 4);
        mv[0]+=v0.x; mv[1]+=v0.y; mv[2]+=v0.z; mv[3]+=v0.w;
        mv[4]+=v1.x; mv[5]+=v1.y; mv[6]+=v1.z; mv[7]+=v1.w;
        den += pden[(pb+cc)*64 + rowin];
    }
    float invd = 1.f / fmaxf(den, 1e-6f);
    float mn2o = 0.f;
    #pragma unroll
    for (int i=0;i<8;++i){ mv[i] *= invd; mn2o += mv[i]*mv[i]; }
    // per-head norm over 64 dims: reduce over oct lanes (bits 0-2)
    float mn2 = mn2o;
    mn2 += __shfl_xor(mn2, 1, 64);
    mn2 += __shfl_xor(mn2, 2, 64);
    mn2 += __shfl_xor(mn2, 4, 64);
    float mn = sqrtf(fmaxf(mn2, 1e-12f));
    float g = beta * 0.5f * fast_atanh(fminf(mn, 1.0f-1e-5f)) / mn;   // t_h = g*m_h
    // E-norm^2 = sum_h g^2*mn2 : reduce over head lanes (bits 3-5)
    float tn = g*g*mn2;
    tn += __shfl_xor(tn, 8, 64);
    tn += __shfl_xor(tn, 16, 64);
    tn += __shfl_xor(tn, 32, 64);
    float en = sqrtf(fmaxf(tn, 1e-12f));
    float f = fast_tanh(en)/en;
    float gf = g * f;
    float* dst = out + ((size_t)(b*SS + s))*EE + h*DD + oct*8;
    float4 o0 = {gf*mv[0], gf*mv[1], gf*mv[2], gf*mv[3]};
    float4 o1 = {gf*mv[4], gf*mv[5], gf*mv[6], gf*mv[7]};
    *(float4*)(dst)     = o0;
    *(float4*)(dst + 4) = o1;
}

extern "C" void kernel_launch(void* const* d_in, const int* in_sizes, int n_in,
                              void* d_out, int out_size, void* d_ws, size_t ws_size,
                              hipStream_t stream) {
    const float* q_in  = (const float*)d_in[0];
    const float* k_in  = (const float*)d_in[1];
    const float* v_in  = (const float*)d_in[2];
    const float* Wq    = (const float*)d_in[3];
    const float* Wk    = (const float*)d_in[4];
    const float* Wv    = (const float*)d_in[5];
    const float* bq    = (const float*)d_in[6];
    const float* bk    = (const float*)d_in[7];
    const float* bv    = (const float*)d_in[8];
    const float* tau   = (const float*)d_in[9];
    const float* gamma = (const float*)d_in[10];
    float* out = (float*)d_out;

    char* ws = (char*)d_ws;
    u16t*  Tlog = (u16t*)(ws + 0);            // 12,582,912 B
    u16t*  Wb   = (u16t*)(ws + 12582912);     //  1,572,864 B
    u16t*  Ub   = (u16t*)(ws + 14155776);     // 12,582,912 B bf16
    u16t*  Qb   = (u16t*)(ws + 26738688);     //  4,194,304 B
    u16t*  Kb   = (u16t*)(ws + 30932992);     //  4,194,304 B
    u16t*  VTb  = (u16t*)(ws + 35127296);     //  4,194,304 B  (V^T * lambda)
    float* qn2  = (float*)(ws + 39321600);    //    131,072 B
    float* kn2  = (float*)(ws + 39452672);    //    131,072 B
    float* lam1 = (float*)(ws + 39583744);    //    131,072 B
    float* pnum = (float*)(ws + 39714816);    // 16*80*4096*4 = 20,971,520 B
    float* pden = (float*)(ws + 60686336);    // 16*80*64*4   =    327,680 B

    // beta-concatenation ratio: exp(lbeta(E/2,1/2) - lbeta(D/2,1/2))
    double lb1 = std::lgamma(256.0) + std::lgamma(0.5) - std::lgamma(256.5);
    double lb2 = std::lgamma(32.0)  + std::lgamma(0.5) - std::lgamma(32.5);
    float beta = (float)std::exp(lb1 - lb2);

    k_pre<<<3840, 256, 0, stream>>>(q_in, k_in, v_in, Tlog, Wq, Wk, Wv, Wb);
    k_proj<<<1536, 256, 0, stream>>>(Tlog, Wb, bq, bk, bv, Ub);
    k_expmap_split<<<2304, 256, 0, stream>>>(Ub, Qb, Kb, VTb, qn2, kn2, lam1);
    k_attn<<<1280, 256, 0, stream>>>(Qb, Kb, VTb, qn2, kn2, lam1, tau, gamma,
                                     pnum, pden);
    k_post<<<1024, 256, 0, stream>>>(pnum, pden, out, beta);
}